// Round 5
// baseline (1285.008 us; speedup 1.0000x reference)
//
#include <hip/hip_runtime.h>
#include <cstdint>
#include <cstddef>

#define HD 128
#define EDGED 16
#define NODED 64
#define LN_EPS 1e-5f

typedef __bf16 bf16x8 __attribute__((ext_vector_type(8)));
typedef float  f32x4  __attribute__((ext_vector_type(4)));
typedef float  f32x16 __attribute__((ext_vector_type(16)));
typedef _Float16 half2v __attribute__((ext_vector_type(2)));
typedef _Float16 half4v __attribute__((ext_vector_type(4)));

__device__ __forceinline__ float gelu_exact(float x) {
    return 0.5f * x * (1.0f + erff(x * 0.7071067811865475f));
}

// fp32 -> bf16 hi/lo split (a ~= hi + lo, lo captures the rounding residual)
__global__ void wconv_k(const float* __restrict__ in, __bf16* __restrict__ hi,
                        __bf16* __restrict__ lo, int n) {
    int i = blockIdx.x * blockDim.x + threadIdx.x;
    if (i < n) {
        float v = in[i];
        __bf16 h = (__bf16)v;
        hi[i] = h;
        lo[i] = (__bf16)(v - (float)h);
    }
}

// ---------------- CSR build ----------------

__global__ void hist_k(const int* __restrict__ ei, int* __restrict__ cnt, int E) {
    int e = blockIdx.x * blockDim.x + threadIdx.x;
    if (e < E) atomicAdd(&cnt[ei[E + e]], 1);
}

__global__ void scan1_k(const int* __restrict__ in, int* __restrict__ out,
                        int* __restrict__ bsum, int n) {
    __shared__ int lds[256];
    int t = threadIdx.x;
    int i = blockIdx.x * 256 + t;
    int v = (i < n) ? in[i] : 0;
    lds[t] = v;
    __syncthreads();
#pragma unroll
    for (int o = 1; o < 256; o <<= 1) {
        int u = (t >= o) ? lds[t - o] : 0;
        __syncthreads();
        lds[t] += u;
        __syncthreads();
    }
    if (i < n) out[i] = lds[t] - v;
    if (t == 255) bsum[blockIdx.x] = lds[255];
}

__global__ void scan2_k(const int* __restrict__ bsum, int* __restrict__ boff, int nb) {
    __shared__ int lds[256];
    int t = threadIdx.x;
    int v = (t < nb) ? bsum[t] : 0;
    lds[t] = v;
    __syncthreads();
#pragma unroll
    for (int o = 1; o < 256; o <<= 1) {
        int u = (t >= o) ? lds[t - o] : 0;
        __syncthreads();
        lds[t] += u;
        __syncthreads();
    }
    if (t < nb) boff[t] = lds[t] - v;
}

// adds block offsets; also emits the scatter cursor copy (saves a d2d memcpy)
__global__ void scan3_k(int* __restrict__ rs, int* __restrict__ cursor,
                        const int* __restrict__ boff, int n, int E) {
    int i = blockIdx.x * 256 + threadIdx.x;
    if (i < n) {
        int v = rs[i] + boff[blockIdx.x];
        rs[i] = v;
        cursor[i] = v;
    }
    if (i == 0) rs[n] = E;
}

__global__ void scatter_k(const int* __restrict__ ei, int* __restrict__ cursor,
                          int2* __restrict__ es, int E) {
    int e = blockIdx.x * blockDim.x + threadIdx.x;
    if (e < E) {
        int dst = ei[E + e];
        int slot = atomicAdd(&cursor[dst], 1);
        es[slot] = make_int2(ei[e], e);
    }
}

// ---------------- edge-LN precompute (+ fused self-loop embed) ----------------
// Also emits the edge-embed weight matrix as MFMA B-fragments (bf16 hi/lo):
// for 32x32x16: lane holds B[k=8*(lane>>5)+j][c=32*tile+(lane&31)], j=0..7.
__global__ void prep_k(const float* __restrict__ edge_W, const float* __restrict__ edge_b,
                       const float* __restrict__ edge_g, const float* __restrict__ edge_be,
                       const float* __restrict__ sl_attr, float* __restrict__ Wg3,
                       float* __restrict__ bg3, float* __restrict__ M3,
                       float* __restrict__ v3, float* __restrict__ s03,
                       float* __restrict__ slv3, __bf16* __restrict__ Wfh3,
                       __bf16* __restrict__ Wfl3)
{
    const int l = blockIdx.x;
    const float* W = edge_W + (size_t)l * HD * EDGED;
    const float* b = edge_b + l * HD;
    const float* g = edge_g + l * HD;
    __shared__ float Wp[HD * EDGED];
    __shared__ float bp[HD];
    __shared__ float wm[EDGED];
    __shared__ float Msh[256];
    __shared__ float vsh[EDGED];
    __shared__ float ash[EDGED];
    __shared__ float bmS, s0sh;
    const int t = threadIdx.x;
#pragma unroll
    for (int m = 0; m < 8; ++m) Wp[m * 256 + t] = W[m * 256 + t];
    __syncthreads();
    if (t < EDGED) {
        float s = 0.f;
        for (int c = 0; c < HD; ++c) s += Wp[c * EDGED + t];
        wm[t] = s * (1.f / HD);
    } else if (t == EDGED) {
        float s = 0.f;
        for (int c = 0; c < HD; ++c) s += b[c];
        bmS = s * (1.f / HD);
    }
    __syncthreads();
    if (t < HD) bp[t] = b[t] - bmS;
    __syncthreads();
#pragma unroll
    for (int m = 0; m < 8; ++m) {
        int idx = m * 256 + t;
        int c = idx >> 4, k = idx & 15;
        float val = Wp[idx] - wm[k];
        Wp[idx] = val;
        Wg3[(size_t)l * 2048 + k * HD + c] = val * g[c];
    }
    if (t < HD) bg3[l * HD + t] = bp[t] * g[t];
    __syncthreads();
    // MFMA B-fragments from centered Wp: idx = tile*512 + lane*8 + j
#pragma unroll
    for (int m = 0; m < 8; ++m) {
        int idx = m * 256 + t;            // 0..2047
        int j  = idx & 7;
        int ln = (idx >> 3) & 63;
        int tt = idx >> 9;
        int k  = 8 * (ln >> 5) + j;
        int c  = 32 * tt + (ln & 31);
        float val = Wp[c * EDGED + k] * g[c];
        __bf16 hh = (__bf16)val;
        Wfh3[(size_t)l * 2048 + idx] = hh;
        Wfl3[(size_t)l * 2048 + idx] = (__bf16)(val - (float)hh);
    }
    {
        int k = t >> 4, j = t & 15;
        float s = 0.f;
        for (int c = 0; c < HD; ++c) s += Wp[c * EDGED + k] * Wp[c * EDGED + j];
        Msh[t] = s;
        M3[l * 256 + t] = s;
    }
    if (t < EDGED) {
        float s = 0.f;
        for (int c = 0; c < HD; ++c) s += Wp[c * EDGED + t] * bp[c];
        vsh[t] = 2.f * s;
        v3[l * EDGED + t] = 2.f * s;
        ash[t] = sl_attr[l * EDGED + t];
    } else if (t == EDGED) {
        float s = 0.f;
        for (int c = 0; c < HD; ++c) s += bp[c] * bp[c];
        s0sh = s;
        s03[l] = s;
    }
    __syncthreads();
    // self-loop embed: out_c = ((Wp.a)*g + bg)*inv + bet, relu
    if (t < HD) {
        float q = s0sh;
#pragma unroll
        for (int k = 0; k < EDGED; ++k) {
            float tk = vsh[k];
#pragma unroll
            for (int j = 0; j < EDGED; ++j) tk = fmaf(Msh[k * 16 + j], ash[j], tk);
            q = fmaf(ash[k], tk, q);
        }
        float inv = rsqrtf(q * (1.f / HD) + LN_EPS);
        float y = 0.f;
#pragma unroll
        for (int k = 0; k < EDGED; ++k) y = fmaf(Wp[t * EDGED + k], ash[k], y);
        slv3[l * HD + t] = fmaxf(fmaf(fmaf(y, g[t], bg3[l * HD + t]), inv, edge_be[l * HD + t]), 0.f);
    }
}

// Per CSR slot: gather attr row once, emit (src, inv-std bits) int2 per layer.
// Also emits the attr row PERMUTED into slot order (attr_p).
__launch_bounds__(256)
__global__ void einv_k(const int2* __restrict__ es, const float* __restrict__ eattr,
                       const float* __restrict__ M3, const float* __restrict__ v3,
                       const float* __restrict__ s03, int2* __restrict__ sei,
                       float* __restrict__ attr_p, int E)
{
    __shared__ float Ms[3 * 256];
    __shared__ float vs[3 * 16];
    __shared__ float s0s[4];
    const int t = threadIdx.x;
    for (int i = t; i < 768; i += 256) Ms[i] = M3[i];
    if (t < 48) vs[t] = v3[t];
    if (t < 3) s0s[t] = s03[t];
    __syncthreads();
    int slot = blockIdx.x * 256 + t;
    if (slot >= E) return;
    int2 se = es[slot];
    const float4* ap = (const float4*)(eattr + (size_t)se.y * EDGED);
    float4 A0 = ap[0], A1 = ap[1], A2 = ap[2], A3 = ap[3];
    float4* op = (float4*)(attr_p + (size_t)slot * EDGED);
    op[0] = A0; op[1] = A1; op[2] = A2; op[3] = A3;
    float a[16] = {A0.x, A0.y, A0.z, A0.w, A1.x, A1.y, A1.z, A1.w,
                   A2.x, A2.y, A2.z, A2.w, A3.x, A3.y, A3.z, A3.w};
#pragma unroll
    for (int l = 0; l < 3; ++l) {
        float q = s0s[l];
#pragma unroll
        for (int k = 0; k < 16; ++k) {
            const float* Mr = &Ms[l * 256 + k * 16];
            float tk = vs[l * 16 + k];
#pragma unroll
            for (int j = 0; j < 16; ++j) tk = fmaf(Mr[j], a[j], tk);
            q = fmaf(a[k], tk, q);
        }
        float iv = rsqrtf(q * (1.f / HD) + LN_EPS);
        sei[(size_t)l * E + slot] = make_int2(se.x, __float_as_int(iv));
    }
}

// ---------------- MFMA GEMM v2: bf16 hi/lo inputs, reg double-buffer --------
template<int K, int NC, int ACT, int STATS, int OUTBF>
__launch_bounds__(256)
__global__ void mgemm_k(const __bf16* __restrict__ Ahi, const __bf16* __restrict__ Alo,
                        const __bf16* __restrict__ Whi, const __bf16* __restrict__ Wlo,
                        const float* __restrict__ bias, float* __restrict__ C,
                        __bf16* __restrict__ Chi, __bf16* __restrict__ Clo,
                        int M, float* __restrict__ stats)
{
    constexpr int RG = 2;
    constexpr int NT = 4;
    constexpr int NK = K / 32;
    __shared__ float st_lds[2][64];

    const int t    = threadIdx.x;
    const int lane = t & 63;
    const int wv   = t >> 6;
    const int ln15 = lane & 15;
    const int quad = lane >> 4;
    const int row_base = blockIdx.x * 128 + wv * 32;
    const int col0 = blockIdx.y * 64;

    f32x4 acc[RG][NT];
#pragma unroll
    for (int g = 0; g < RG; ++g)
#pragma unroll
        for (int nt = 0; nt < NT; ++nt)
#pragma unroll
            for (int r = 0; r < 4; ++r) acc[g][nt][r] = 0.f;

    size_t arow[RG];
#pragma unroll
    for (int g = 0; g < RG; ++g) {
        int row = row_base + g * 16 + ln15;
        row = row < M ? row : M - 1;          // clamp: junk values, store masked
        arow[g] = (size_t)row * K + quad * 8;
    }
    size_t brow[NT];
#pragma unroll
    for (int nt = 0; nt < NT; ++nt)
        brow[nt] = (size_t)(col0 + nt * 16 + ln15) * K + quad * 8;

    bf16x8 a0h[RG], a0l[RG], a1h[RG], a1l[RG];
    bf16x8 b0h[NT], b0l[NT], b1h[NT], b1l[NT];

#define LD_A(kc, AH, AL) { \
    _Pragma("unroll") \
    for (int g = 0; g < RG; ++g) { \
        AH[g] = *(const bf16x8*)(Ahi + arow[g] + (kc)); \
        AL[g] = *(const bf16x8*)(Alo + arow[g] + (kc)); \
    } }
#define LD_B(kc, BH, BL) { \
    _Pragma("unroll") \
    for (int nt = 0; nt < NT; ++nt) { \
        BH[nt] = *(const bf16x8*)(Whi + brow[nt] + (kc)); \
        BL[nt] = *(const bf16x8*)(Wlo + brow[nt] + (kc)); \
    } }
#define DO_MFMA(AH, AL, BH, BL) { \
    _Pragma("unroll") \
    for (int nt = 0; nt < NT; ++nt) { \
        _Pragma("unroll") \
        for (int g = 0; g < RG; ++g) { \
            acc[g][nt] = __builtin_amdgcn_mfma_f32_16x16x32_bf16(AH[g], BH[nt], acc[g][nt], 0, 0, 0); \
            acc[g][nt] = __builtin_amdgcn_mfma_f32_16x16x32_bf16(AH[g], BL[nt], acc[g][nt], 0, 0, 0); \
            acc[g][nt] = __builtin_amdgcn_mfma_f32_16x16x32_bf16(AL[g], BH[nt], acc[g][nt], 0, 0, 0); \
        } } }

    LD_A(0, a0h, a0l);
    LD_B(0, b0h, b0l);
    for (int s = 0; s < NK; s += 2) {
        LD_A((s + 1) * 32, a1h, a1l);
        LD_B((s + 1) * 32, b1h, b1l);
        DO_MFMA(a0h, a0l, b0h, b0l);
        if (s + 2 < NK) {
            LD_A((s + 2) * 32, a0h, a0l);
            LD_B((s + 2) * 32, b0h, b0l);
        }
        DO_MFMA(a1h, a1l, b1h, b1l);
    }
#undef LD_A
#undef LD_B
#undef DO_MFMA

    if (STATS) {
        if (t < 64) { st_lds[0][t] = 0.f; st_lds[1][t] = 0.f; }
        __syncthreads();
    }

    float bv[NT];
#pragma unroll
    for (int nt = 0; nt < NT; ++nt) bv[nt] = bias[col0 + nt * 16 + ln15];

    float s1[NT], s2[NT];
#pragma unroll
    for (int nt = 0; nt < NT; ++nt) { s1[nt] = 0.f; s2[nt] = 0.f; }

#pragma unroll
    for (int g = 0; g < RG; ++g)
#pragma unroll
        for (int r = 0; r < 4; ++r) {
            int row = row_base + g * 16 + quad * 4 + r;
            if (row < M) {
#pragma unroll
                for (int nt = 0; nt < NT; ++nt) {
                    float v = acc[g][nt][r] + bv[nt];
                    if (ACT == 1) v = gelu_exact(v);
                    size_t ci = (size_t)row * NC + col0 + nt * 16 + ln15;
                    if (OUTBF) {
                        __bf16 hh = (__bf16)v;
                        Chi[ci] = hh;
                        Clo[ci] = (__bf16)(v - (float)hh);
                    } else {
                        C[ci] = v;
                    }
                    if (STATS) { s1[nt] += v; s2[nt] += v * v; }
                }
            }
        }

    if (STATS) {
#pragma unroll
        for (int nt = 0; nt < NT; ++nt) {
            atomicAdd(&st_lds[0][nt * 16 + ln15], s1[nt]);
            atomicAdd(&st_lds[1][nt * 16 + ln15], s2[nt]);
        }
        __syncthreads();
        if (t < 64) {
            atomicAdd(&stats[col0 + t],      st_lds[0][t]);
            atomicAdd(&stats[HD + col0 + t], st_lds[1][t]);
        }
    }
}

// LayerNorm(+ReLU) over rows of 128, one wave per node; fp16 output
__global__ void ln_relu_k(const float* __restrict__ y, const float* __restrict__ gam,
                          const float* __restrict__ bet, _Float16* __restrict__ h16, int N)
{
    int lane = threadIdx.x & 63;
    int c0 = lane * 2;
    float2 g2 = *(const float2*)&gam[c0];
    float2 b2 = *(const float2*)&bet[c0];
    int wid = (blockIdx.x * blockDim.x + threadIdx.x) >> 6;
    int nw  = (gridDim.x * blockDim.x) >> 6;
    for (int n = wid; n < N; n += nw) {
        float2 v = *(const float2*)&y[(size_t)n * HD + c0];
        float s = v.x + v.y;
        float q = v.x * v.x + v.y * v.y;
#pragma unroll
        for (int o = 32; o > 0; o >>= 1) { s += __shfl_xor(s, o, 64); q += __shfl_xor(q, o, 64); }
        float mu  = s * (1.f / 128.f);
        float inv = rsqrtf(q * (1.f / 128.f) - mu * mu + LN_EPS);
        half2v r;
        r.x = (_Float16)fmaxf(fmaf((v.x - mu) * inv, g2.x, b2.x), 0.f);
        r.y = (_Float16)fmaxf(fmaf((v.y - mu) * inv, g2.y, b2.y), 0.f);
        *(half2v*)&h16[(size_t)n * HD + c0] = r;
    }
}

// ---------------- pull aggregation v7: MFMA edge-embed ---------------------
// Per 32-edge chunk: D[32 edges][32 ch] = attr[32x16] x W[16x32] via
// mfma_f32_32x32x16_bf16 (4 ch-tiles x 3 hi/lo MFMAs). A-frag: lane holds
// attr[edge=lane&31][k=8*(lane>>5)..+7] = 2 contiguous float4 of attr_p, fully
// coalesced. C-init = bg[ch]. Post: relu(d*iv[edge]+bt[ch]) masked-summed into
// per-channel partials (D rows = edges). h-gather stays in channel-pair layout
// (lane owns {2l,2l+1}); the two layouts merge via a 512B/node LDS roundtrip.
// Kills the 4KB/edge LDS broadcast + ~32 VALU FMA/edge of v6.
__launch_bounds__(256)
__global__ void pull7_k(const _Float16* __restrict__ h16, const int* __restrict__ rs,
                        const float* __restrict__ attr_p, const int2* __restrict__ sei,
                        const float* __restrict__ slv, const __bf16* __restrict__ Wfh,
                        const __bf16* __restrict__ Wfl, const float* __restrict__ bg,
                        const float* __restrict__ bet, __bf16* __restrict__ Ahi,
                        __bf16* __restrict__ Alo, int N)
{
    __shared__ float alds_all[4][HD];           // 2 KB: per-wave layout merge
    const int t = threadIdx.x;
    const int lane = t & 63;
    const int wv = t >> 6;
    float* alds = alds_all[wv];

    const int c0 = lane * 2;
    const int l31 = lane & 31;
    const int half = lane >> 5;
    const int rowbase = half * 4;               // D-row base for this lane
    const int koff4 = half * 2;                 // float4 idx of A-frag k-offset

    // W-fragments (bf16 hi/lo) + per-channel constants, channel = l31 + 32*tt
    bf16x8 wh[4], wl[4];
    float bgt[4], btt[4];
#pragma unroll
    for (int tt = 0; tt < 4; ++tt) {
        wh[tt] = *(const bf16x8*)&Wfh[tt * 512 + lane * 8];
        wl[tt] = *(const bf16x8*)&Wfl[tt * 512 + lane * 8];
        bgt[tt] = bg[l31 + 32 * tt];
        btt[tt] = bet[l31 + 32 * tt];
    }
    const float2 slvv = *(const float2*)&slv[c0];

    const int stride = gridDim.x << 2;
    const float4* ap4 = (const float4*)attr_p;

    int n = (blockIdx.x << 2) + wv;
    if (n >= N) return;

    // ---- pipeline prologue: prefetch node n's chunk0 + rs one ahead ----
    int rb0 = rs[n], re0 = rs[n + 1];
    int n1 = n + stride;
    int rb1 = 0, re1 = 0;
    if (n1 < N) { rb1 = rs[n1]; re1 = rs[n1 + 1]; }
    int m0 = re0 - rb0; if (m0 > 32) m0 = 32;
    int2 sv = make_int2(0, 0);
    if (lane < m0) sv = sei[rb0 + lane];
    float4 av0 = make_float4(0.f, 0.f, 0.f, 0.f), av1 = av0;
    if (l31 < m0) {
        av0 = ap4[(size_t)(rb0 + l31) * 4 + koff4];
        av1 = ap4[(size_t)(rb0 + l31) * 4 + koff4 + 1];
    }

#define CHUNK(AV0, AV1, SVX, MCX) { \
        float af[8] = {AV0.x, AV0.y, AV0.z, AV0.w, AV1.x, AV1.y, AV1.z, AV1.w}; \
        bf16x8 ah, al; \
        _Pragma("unroll") \
        for (int jj = 0; jj < 8; ++jj) { \
            __bf16 hh = (__bf16)af[jj]; \
            ah[jj] = hh; al[jj] = (__bf16)(af[jj] - (float)hh); \
        } \
        float ivr[16]; \
        _Pragma("unroll") \
        for (int r = 0; r < 16; ++r) { \
            int row = rowbase + (r & 3) + 8 * (r >> 2); \
            ivr[r] = __int_as_float(__shfl((SVX).y, row, 64)); \
        } \
        _Pragma("unroll") \
        for (int tt = 0; tt < 4; ++tt) { \
            f32x16 d; \
            _Pragma("unroll") \
            for (int r = 0; r < 16; ++r) d[r] = bgt[tt]; \
            d = __builtin_amdgcn_mfma_f32_32x32x16_bf16(ah, wh[tt], d, 0, 0, 0); \
            d = __builtin_amdgcn_mfma_f32_32x32x16_bf16(ah, wl[tt], d, 0, 0, 0); \
            d = __builtin_amdgcn_mfma_f32_32x32x16_bf16(al, wh[tt], d, 0, 0, 0); \
            _Pragma("unroll") \
            for (int r = 0; r < 16; ++r) { \
                int row = rowbase + (r & 3) + 8 * (r >> 2); \
                float v = fmaxf(fmaf(d[r], ivr[r], btt[tt]), 0.f); \
                pacc[tt] += (row < (MCX)) ? v : 0.f; \
            } \
        } \
        int j_ = 0; \
        for (; j_ + 4 <= (MCX); j_ += 4) { \
            int s_0 = __shfl((SVX).x, j_,     64); \
            int s_1 = __shfl((SVX).x, j_ + 1, 64); \
            int s_2 = __shfl((SVX).x, j_ + 2, 64); \
            int s_3 = __shfl((SVX).x, j_ + 3, 64); \
            half2v g0 = *(const half2v*)&h16[(size_t)s_0 * HD + c0]; \
            half2v g1 = *(const half2v*)&h16[(size_t)s_1 * HD + c0]; \
            half2v g2 = *(const half2v*)&h16[(size_t)s_2 * HD + c0]; \
            half2v g3 = *(const half2v*)&h16[(size_t)s_3 * HD + c0]; \
            gacc0 += ((float)g0.x + (float)g1.x) + ((float)g2.x + (float)g3.x); \
            gacc1 += ((float)g0.y + (float)g1.y) + ((float)g2.y + (float)g3.y); \
        } \
        for (; j_ < (MCX); ++j_) { \
            int s_ = __shfl((SVX).x, j_, 64); \
            half2v gj = *(const half2v*)&h16[(size_t)s_ * HD + c0]; \
            gacc0 += (float)gj.x; \
            gacc1 += (float)gj.y; \
        } \
    }

    while (n < N) {
        const int  curb = rb0, cure = re0, mc = m0;
        const int2 svc  = sv;
        const float4 ac0 = av0, ac1 = av1;

        // ---- advance pipeline: issue node n+1's loads before computing n ----
        int n2 = n1 + stride;
        int rb2 = 0, re2 = 0;
        if (n2 < N) { rb2 = rs[n2]; re2 = rs[n2 + 1]; }
        int mn = re1 - rb1; if (mn > 32) mn = 32;
        int2 svn = make_int2(0, 0);
        if (lane < mn) svn = sei[rb1 + lane];
        float4 b0v = make_float4(0.f, 0.f, 0.f, 0.f), b1v = b0v;
        if (l31 < mn) {
            b0v = ap4[(size_t)(rb1 + l31) * 4 + koff4];
            b1v = ap4[(size_t)(rb1 + l31) * 4 + koff4 + 1];
        }

        // ---- compute node n ----
        half2v hs = *(const half2v*)&h16[(size_t)n * HD + c0];
        float gacc0 = (float)hs.x + slvv.x;
        float gacc1 = (float)hs.y + slvv.y;
        float pacc[4] = {0.f, 0.f, 0.f, 0.f};

        CHUNK(ac0, ac1, svc, mc);

        // rare: degree > 32 — inline chunks
        for (int sb = curb + 32; sb < cure; sb += 32) {
            int mx = cure - sb; if (mx > 32) mx = 32;
            int2 svx = make_int2(0, 0);
            if (lane < mx) svx = sei[sb + lane];
            float4 x0 = make_float4(0.f, 0.f, 0.f, 0.f), x1 = x0;
            if (l31 < mx) {
                x0 = ap4[(size_t)(sb + l31) * 4 + koff4];
                x1 = ap4[(size_t)(sb + l31) * 4 + koff4 + 1];
            }
            CHUNK(x0, x1, svx, mx);
        }

        // ---- merge MFMA-layout partials into channel-pair layout ----
#pragma unroll
        for (int tt = 0; tt < 4; ++tt) pacc[tt] += __shfl_xor(pacc[tt], 32, 64);
        if (lane < 32) {
#pragma unroll
            for (int tt = 0; tt < 4; ++tt) alds[32 * tt + lane] = pacc[tt];
        }
        float2 mv = *(const float2*)&alds[c0];
        float o0 = gacc0 + mv.x;
        float o1 = gacc1 + mv.y;

        // ---- store node n (bf16 hi/lo packed) ----
        __bf16 b0 = (__bf16)o0, b1 = (__bf16)o1;
        union { __bf16 b[2]; unsigned u; } ph, pl;
        ph.b[0] = b0;
        ph.b[1] = b1;
        pl.b[0] = (__bf16)(o0 - (float)b0);
        pl.b[1] = (__bf16)(o1 - (float)b1);
        *(unsigned*)&Ahi[(size_t)n * HD + c0] = ph.u;
        *(unsigned*)&Alo[(size_t)n * HD + c0] = pl.u;

        // ---- rotate pipeline ----
        n = n1; n1 = n2;
        rb0 = rb1; re0 = re1; rb1 = rb2; re1 = re2;
        m0 = mn; sv = svn; av0 = b0v; av1 = b1v;
    }
#undef CHUNK
}

// BatchNorm apply from accumulated column sums; optional ReLU.
// out16 != null -> write fp16 (h for next layer); else fp32 to out32.
__global__ void bn_k(const float* __restrict__ hl, const float* __restrict__ stats,
                     const float* __restrict__ gam, const float* __restrict__ bet,
                     float* __restrict__ out32, _Float16* __restrict__ out16,
                     int total4, float invN, int relu)
{
    int idx = blockIdx.x * blockDim.x + threadIdx.x;
    if (idx < total4) {
        int c4 = idx & 31;
        float4 x  = ((const float4*)hl)[idx];
        float4 s1 = ((const float4*)stats)[c4];
        float4 s2 = ((const float4*)stats)[32 + c4];
        float4 g  = ((const float4*)gam)[c4];
        float4 b  = ((const float4*)bet)[c4];
        float4 r;
        {
            float m = s1.x * invN; float v = s2.x * invN - m * m;
            r.x = fmaf((x.x - m) * rsqrtf(v + LN_EPS), g.x, b.x);
        }
        {
            float m = s1.y * invN; float v = s2.y * invN - m * m;
            r.y = fmaf((x.y - m) * rsqrtf(v + LN_EPS), g.y, b.y);
        }
        {
            float m = s1.z * invN; float v = s2.z * invN - m * m;
            r.z = fmaf((x.z - m) * rsqrtf(v + LN_EPS), g.z, b.z);
        }
        {
            float m = s1.w * invN; float v = s2.w * invN - m * m;
            r.w = fmaf((x.w - m) * rsqrtf(v + LN_EPS), g.w, b.w);
        }
        if (relu) {
            r.x = fmaxf(r.x, 0.f); r.y = fmaxf(r.y, 0.f);
            r.z = fmaxf(r.z, 0.f); r.w = fmaxf(r.w, 0.f);
        }
        if (out16) {
            half4v o;
            o.x = (_Float16)r.x; o.y = (_Float16)r.y;
            o.z = (_Float16)r.z; o.w = (_Float16)r.w;
            *(half4v*)&out16[(size_t)idx * 4] = o;
        } else {
            ((float4*)out32)[idx] = r;
        }
    }
}

extern "C" void kernel_launch(void* const* d_in, const int* in_sizes, int n_in,
                              void* d_out, int out_size, void* d_ws, size_t ws_size,
                              hipStream_t stream)
{
    const float* x       = (const float*)d_in[0];
    const int*   ei      = (const int*)d_in[1];
    const float* eattr   = (const float*)d_in[2];
    const float* node_W  = (const float*)d_in[3];
    const float* node_b  = (const float*)d_in[4];
    const float* node_g  = (const float*)d_in[5];
    const float* node_be = (const float*)d_in[6];
    const float* edge_W  = (const float*)d_in[7];
    const float* edge_b  = (const float*)d_in[8];
    const float* edge_g  = (const float*)d_in[9];
    const float* edge_be = (const float*)d_in[10];
    const float* sl_attr = (const float*)d_in[11];
    const float* W1      = (const float*)d_in[12];
    const float* b1      = (const float*)d_in[13];
    const float* W2      = (const float*)d_in[14];
    const float* b2      = (const float*)d_in[15];
    const float* bn_g    = (const float*)d_in[16];
    const float* bn_b    = (const float*)d_in[17];

    const int N = in_sizes[0] / NODED;
    const int E = in_sizes[1] / 2;

    // explicit 16B-aligned workspace layout
    char* base = (char*)d_ws;
    size_t off = 0;
    auto take = [&](size_t nbytes) -> void* {
        void* p = base + off;
        off = (off + nbytes + 15) & ~(size_t)15;
        return p;
    };
    _Float16* h16  = (_Float16*)take((size_t)N * HD * 2); // node features (fp16)
    float*  z      = (float*)take((size_t)N * HD * 4);     // node-embed pre-LN (fp32)
    __bf16* aghi   = (__bf16*)take((size_t)N * HD * 2);    // aggr bf16 hi
    __bf16* aglo   = (__bf16*)take((size_t)N * HD * 2);
    __bf16* zhi    = (__bf16*)take((size_t)N * 256 * 2);   // mlp1 out bf16 hi
    __bf16* zlo    = (__bf16*)take((size_t)N * 256 * 2);
    __bf16* xhi    = (__bf16*)take((size_t)N * NODED * 2);
    __bf16* xlo    = (__bf16*)take((size_t)N * NODED * 2);
    float*  slv3   = (float*)take(3 * HD * 4);
    float*  stats  = (float*)take(3 * 256 * 4);
    int*    cnt    = (int*)take((size_t)N * 4);
    int*    cursor = (int*)take((size_t)N * 4);
    int*    bsum   = (int*)take(256 * 4);
    int*    boff   = (int*)take(256 * 4);
    int*    rs     = (int*)take(((size_t)N + 2) * 4);
    int2*   es     = (int2*)take((size_t)E * 8);
    int2*   sei    = (int2*)take((size_t)3 * E * 8);       // (src, inv-std bits)
    float*  attr_p = (float*)take((size_t)E * EDGED * 4);  // slot-permuted attrs
    float*  Wg3    = (float*)take(3 * 2048 * 4);
    float*  bg3    = (float*)take(3 * HD * 4);
    float*  M3     = (float*)take(3 * 256 * 4);
    float*  v3     = (float*)take(3 * 16 * 4);
    float*  s03    = (float*)take(4 * 4);
    __bf16* Wfh3   = (__bf16*)take(3 * 2048 * 2);          // MFMA B-frags hi
    __bf16* Wfl3   = (__bf16*)take(3 * 2048 * 2);          // MFMA B-frags lo
    __bf16* nWhi   = (__bf16*)take((size_t)HD * NODED * 2);
    __bf16* nWlo   = (__bf16*)take((size_t)HD * NODED * 2);
    __bf16* W1hi   = (__bf16*)take((size_t)3 * 256 * HD * 2);
    __bf16* W1lo   = (__bf16*)take((size_t)3 * 256 * HD * 2);
    __bf16* W2hi   = (__bf16*)take((size_t)3 * HD * 256 * 2);
    __bf16* W2lo   = (__bf16*)take((size_t)3 * HD * 256 * 2);

    // bf16 hi/lo splits: weights ([N][K] row-major already) and x
    wconv_k<<<(HD * NODED + 255) / 256, 256, 0, stream>>>(node_W, nWhi, nWlo, HD * NODED);
    wconv_k<<<(3 * 256 * HD + 255) / 256, 256, 0, stream>>>(W1, W1hi, W1lo, 3 * 256 * HD);
    wconv_k<<<(3 * 256 * HD + 255) / 256, 256, 0, stream>>>(W2, W2hi, W2lo, 3 * 256 * HD);
    wconv_k<<<((int)((size_t)N * NODED + 255) / 256), 256, 0, stream>>>(x, xhi, xlo, N * NODED);

    // edge-LN precompute + self-loop embed + MFMA W-frags (all 3 layers)
    prep_k<<<3, 256, 0, stream>>>(edge_W, edge_b, edge_g, edge_be, sl_attr,
                                  Wg3, bg3, M3, v3, s03, slv3, Wfh3, Wfl3);

    // ---- CSR build ----
    const int eblocks = (E + 255) / 256;
    const int nblocks = (N + 255) / 256;
    hipMemsetAsync(cnt, 0, (size_t)N * sizeof(int), stream);
    hist_k<<<eblocks, 256, 0, stream>>>(ei, cnt, E);
    scan1_k<<<nblocks, 256, 0, stream>>>(cnt, rs, bsum, N);
    scan2_k<<<1, 256, 0, stream>>>(bsum, boff, nblocks);
    scan3_k<<<nblocks, 256, 0, stream>>>(rs, cursor, boff, N, E);
    scatter_k<<<eblocks, 256, 0, stream>>>(ei, cursor, es, E);

    // per-slot (src, inv-std) for all 3 layers + permuted attr stream
    einv_k<<<eblocks, 256, 0, stream>>>(es, eattr, M3, v3, s03, sei, attr_p, E);

    const int total4  = N * (HD / 4);
    const int vblocks = (total4 + 255) / 256;
    const int gb128   = (N + 127) / 128;
    int pgrid = (N + 3) / 4;
    if (pgrid > 2048) pgrid = 2048;           // persistent: 8192 waves

    // node embed: Linear (MFMA) -> LN -> ReLU
    mgemm_k<NODED, HD, 0, 0, 0><<<dim3(gb128, 2), 256, 0, stream>>>(
        xhi, xlo, nWhi, nWlo, node_b, z, nullptr, nullptr, N, nullptr);
    ln_relu_k<<<(N + 3) / 4, 256, 0, stream>>>(z, node_g, node_be, h16, N);

    hipMemsetAsync(stats, 0, 3 * 256 * sizeof(float), stream);

    for (int l = 0; l < 3; ++l) {
        pull7_k<<<pgrid, 256, 0, stream>>>(h16, rs, attr_p, sei + (size_t)l * E,
                                           slv3 + l * HD,
                                           Wfh3 + (size_t)l * 2048,
                                           Wfl3 + (size_t)l * 2048,
                                           bg3 + l * HD, edge_be + l * HD,
                                           aghi, aglo, N);

        mgemm_k<HD, 256, 1, 0, 1><<<dim3(gb128, 4), 256, 0, stream>>>(
            aghi, aglo, W1hi + (size_t)l * 256 * HD, W1lo + (size_t)l * 256 * HD,
            b1 + l * 256, nullptr, zhi, zlo, N, nullptr);

        mgemm_k<256, HD, 0, 1, 0><<<dim3(gb128, 2), 256, 0, stream>>>(
            zhi, zlo, W2hi + (size_t)l * HD * 256, W2lo + (size_t)l * HD * 256,
            b2 + l * HD, (float*)d_out, nullptr, nullptr, N, stats + l * 256);

        bn_k<<<vblocks, 256, 0, stream>>>((const float*)d_out, stats + l * 256,
                                          bn_g + l * HD, bn_b + l * HD,
                                          (float*)d_out, (l < 2) ? h16 : nullptr,
                                          total4, 1.f / N, (l < 2) ? 1 : 0);
    }
}

// Round 6
// 883.341 us; speedup vs baseline: 1.4547x; 1.4547x over previous
//
#include <hip/hip_runtime.h>
#include <cstdint>
#include <cstddef>

#define HD 128
#define EDGED 16
#define NODED 64
#define LN_EPS 1e-5f

typedef __bf16 bf16x8 __attribute__((ext_vector_type(8)));
typedef float  f32x4  __attribute__((ext_vector_type(4)));
typedef _Float16 half2v __attribute__((ext_vector_type(2)));
typedef _Float16 half4v __attribute__((ext_vector_type(4)));
typedef _Float16 half8v __attribute__((ext_vector_type(8)));

union HU { half8v v; half2v p[4]; };

__device__ __forceinline__ float gelu_exact(float x) {
    return 0.5f * x * (1.0f + erff(x * 0.7071067811865475f));
}

// fp32 -> bf16 hi/lo split (a ~= hi + lo, lo captures the rounding residual)
__global__ void wconv_k(const float* __restrict__ in, __bf16* __restrict__ hi,
                        __bf16* __restrict__ lo, int n) {
    int i = blockIdx.x * blockDim.x + threadIdx.x;
    if (i < n) {
        float v = in[i];
        __bf16 h = (__bf16)v;
        hi[i] = h;
        lo[i] = (__bf16)(v - (float)h);
    }
}

// ---------------- CSR build ----------------

__global__ void hist_k(const int* __restrict__ ei, int* __restrict__ cnt, int E) {
    int e = blockIdx.x * blockDim.x + threadIdx.x;
    if (e < E) atomicAdd(&cnt[ei[E + e]], 1);
}

__global__ void scan1_k(const int* __restrict__ in, int* __restrict__ out,
                        int* __restrict__ bsum, int n) {
    __shared__ int lds[256];
    int t = threadIdx.x;
    int i = blockIdx.x * 256 + t;
    int v = (i < n) ? in[i] : 0;
    lds[t] = v;
    __syncthreads();
#pragma unroll
    for (int o = 1; o < 256; o <<= 1) {
        int u = (t >= o) ? lds[t - o] : 0;
        __syncthreads();
        lds[t] += u;
        __syncthreads();
    }
    if (i < n) out[i] = lds[t] - v;
    if (t == 255) bsum[blockIdx.x] = lds[255];
}

__global__ void scan2_k(const int* __restrict__ bsum, int* __restrict__ boff, int nb) {
    __shared__ int lds[256];
    int t = threadIdx.x;
    int v = (t < nb) ? bsum[t] : 0;
    lds[t] = v;
    __syncthreads();
#pragma unroll
    for (int o = 1; o < 256; o <<= 1) {
        int u = (t >= o) ? lds[t - o] : 0;
        __syncthreads();
        lds[t] += u;
        __syncthreads();
    }
    if (t < nb) boff[t] = lds[t] - v;
}

// adds block offsets; also emits the scatter cursor copy (saves a d2d memcpy)
__global__ void scan3_k(int* __restrict__ rs, int* __restrict__ cursor,
                        const int* __restrict__ boff, int n, int E) {
    int i = blockIdx.x * 256 + threadIdx.x;
    if (i < n) {
        int v = rs[i] + boff[blockIdx.x];
        rs[i] = v;
        cursor[i] = v;
    }
    if (i == 0) rs[n] = E;
}

__global__ void scatter_k(const int* __restrict__ ei, int* __restrict__ cursor,
                          int2* __restrict__ es, int E) {
    int e = blockIdx.x * blockDim.x + threadIdx.x;
    if (e < E) {
        int dst = ei[E + e];
        int slot = atomicAdd(&cursor[dst], 1);
        es[slot] = make_int2(ei[e], e);
    }
}

// ---------------- edge-LN precompute (+ fused self-loop embed) ----------------
// Per layer l: wm[k]=mean_c W[c][k]; bm=mean(b); Wp=W-wm; bp=b-bm.
// Wg16[c][k] = (fp16)(Wp[c][k]*g[c]); bg[c] = bp[c]*g[c]
// M[k][j] = sum_c Wp[c][k]*Wp[c][j]; v[k]=2*sum_c Wp[c][k]*bp[c]; s0=sum bp^2
// Tail: embeds the learned self-loop attr for this layer into slv3[l].
__global__ void prep_k(const float* __restrict__ edge_W, const float* __restrict__ edge_b,
                       const float* __restrict__ edge_g, const float* __restrict__ edge_be,
                       const float* __restrict__ sl_attr, _Float16* __restrict__ Wg16_3,
                       float* __restrict__ bg3, float* __restrict__ M3,
                       float* __restrict__ v3, float* __restrict__ s03,
                       float* __restrict__ slv3)
{
    const int l = blockIdx.x;
    const float* W = edge_W + (size_t)l * HD * EDGED;
    const float* b = edge_b + l * HD;
    const float* g = edge_g + l * HD;
    __shared__ float Wp[HD * EDGED];
    __shared__ float bp[HD];
    __shared__ float wm[EDGED];
    __shared__ float Msh[256];
    __shared__ float vsh[EDGED];
    __shared__ float ash[EDGED];
    __shared__ float bmS, s0sh;
    const int t = threadIdx.x;
#pragma unroll
    for (int m = 0; m < 8; ++m) Wp[m * 256 + t] = W[m * 256 + t];
    __syncthreads();
    if (t < EDGED) {
        float s = 0.f;
        for (int c = 0; c < HD; ++c) s += Wp[c * EDGED + t];
        wm[t] = s * (1.f / HD);
    } else if (t == EDGED) {
        float s = 0.f;
        for (int c = 0; c < HD; ++c) s += b[c];
        bmS = s * (1.f / HD);
    }
    __syncthreads();
    if (t < HD) bp[t] = b[t] - bmS;
    __syncthreads();
#pragma unroll
    for (int m = 0; m < 8; ++m) {
        int idx = m * 256 + t;
        int c = idx >> 4, k = idx & 15;
        float val = Wp[idx] - wm[k];
        Wp[idx] = val;
        Wg16_3[(size_t)l * 2048 + idx] = (_Float16)(val * g[c]);   // [c][k] layout
    }
    if (t < HD) bg3[l * HD + t] = bp[t] * g[t];
    __syncthreads();
    {
        int k = t >> 4, j = t & 15;
        float s = 0.f;
        for (int c = 0; c < HD; ++c) s += Wp[c * EDGED + k] * Wp[c * EDGED + j];
        Msh[t] = s;
        M3[l * 256 + t] = s;
    }
    if (t < EDGED) {
        float s = 0.f;
        for (int c = 0; c < HD; ++c) s += Wp[c * EDGED + t] * bp[c];
        vsh[t] = 2.f * s;
        v3[l * EDGED + t] = 2.f * s;
        ash[t] = sl_attr[l * EDGED + t];
    } else if (t == EDGED) {
        float s = 0.f;
        for (int c = 0; c < HD; ++c) s += bp[c] * bp[c];
        s0sh = s;
        s03[l] = s;
    }
    __syncthreads();
    // self-loop embed: out_c = ((Wp.a)*g + bg)*inv + bet, relu
    if (t < HD) {
        float q = s0sh;
#pragma unroll
        for (int k = 0; k < EDGED; ++k) {
            float tk = vsh[k];
#pragma unroll
            for (int j = 0; j < EDGED; ++j) tk = fmaf(Msh[k * 16 + j], ash[j], tk);
            q = fmaf(ash[k], tk, q);
        }
        float inv = rsqrtf(q * (1.f / HD) + LN_EPS);
        float y = 0.f;
#pragma unroll
        for (int k = 0; k < EDGED; ++k) y = fmaf(Wp[t * EDGED + k], ash[k], y);
        slv3[l * HD + t] = fmaxf(fmaf(fmaf(y, g[t], bg3[l * HD + t]), inv, edge_be[l * HD + t]), 0.f);
    }
}

// Per CSR slot: gather attr row once, emit (src, inv-std bits) int2 per layer.
// Also emits the attr row PERMUTED into slot order as fp16 (attr16) so the
// pull kernel reads a contiguous half-width stream. Variance math stays fp32.
__launch_bounds__(256)
__global__ void einv_k(const int2* __restrict__ es, const float* __restrict__ eattr,
                       const float* __restrict__ M3, const float* __restrict__ v3,
                       const float* __restrict__ s03, int2* __restrict__ sei,
                       _Float16* __restrict__ attr16, int E)
{
    __shared__ float Ms[3 * 256];
    __shared__ float vs[3 * 16];
    __shared__ float s0s[4];
    const int t = threadIdx.x;
    for (int i = t; i < 768; i += 256) Ms[i] = M3[i];
    if (t < 48) vs[t] = v3[t];
    if (t < 3) s0s[t] = s03[t];
    __syncthreads();
    int slot = blockIdx.x * 256 + t;
    if (slot >= E) return;
    int2 se = es[slot];
    const float4* ap = (const float4*)(eattr + (size_t)se.y * EDGED);
    float4 A0 = ap[0], A1 = ap[1], A2 = ap[2], A3 = ap[3];
    float a[16] = {A0.x, A0.y, A0.z, A0.w, A1.x, A1.y, A1.z, A1.w,
                   A2.x, A2.y, A2.z, A2.w, A3.x, A3.y, A3.z, A3.w};
    {
        half8v o0, o1;
#pragma unroll
        for (int i = 0; i < 8; ++i) { o0[i] = (_Float16)a[i]; o1[i] = (_Float16)a[8 + i]; }
        _Float16* op = attr16 + (size_t)slot * EDGED;
        *(half8v*)&op[0] = o0;
        *(half8v*)&op[8] = o1;
    }
#pragma unroll
    for (int l = 0; l < 3; ++l) {
        float q = s0s[l];
#pragma unroll
        for (int k = 0; k < 16; ++k) {
            const float* Mr = &Ms[l * 256 + k * 16];
            float tk = vs[l * 16 + k];
#pragma unroll
            for (int j = 0; j < 16; ++j) tk = fmaf(Mr[j], a[j], tk);
            q = fmaf(a[k], tk, q);
        }
        float iv = rsqrtf(q * (1.f / HD) + LN_EPS);
        sei[(size_t)l * E + slot] = make_int2(se.x, __float_as_int(iv));
    }
}

// ---------------- MFMA GEMM v2: bf16 hi/lo inputs, reg double-buffer --------
template<int K, int NC, int ACT, int STATS, int OUTBF>
__launch_bounds__(256)
__global__ void mgemm_k(const __bf16* __restrict__ Ahi, const __bf16* __restrict__ Alo,
                        const __bf16* __restrict__ Whi, const __bf16* __restrict__ Wlo,
                        const float* __restrict__ bias, float* __restrict__ C,
                        __bf16* __restrict__ Chi, __bf16* __restrict__ Clo,
                        int M, float* __restrict__ stats)
{
    constexpr int RG = 2;
    constexpr int NT = 4;
    constexpr int NK = K / 32;
    __shared__ float st_lds[2][64];

    const int t    = threadIdx.x;
    const int lane = t & 63;
    const int wv   = t >> 6;
    const int ln15 = lane & 15;
    const int quad = lane >> 4;
    const int row_base = blockIdx.x * 128 + wv * 32;
    const int col0 = blockIdx.y * 64;

    f32x4 acc[RG][NT];
#pragma unroll
    for (int g = 0; g < RG; ++g)
#pragma unroll
        for (int nt = 0; nt < NT; ++nt)
#pragma unroll
            for (int r = 0; r < 4; ++r) acc[g][nt][r] = 0.f;

    size_t arow[RG];
#pragma unroll
    for (int g = 0; g < RG; ++g) {
        int row = row_base + g * 16 + ln15;
        row = row < M ? row : M - 1;          // clamp: junk values, store masked
        arow[g] = (size_t)row * K + quad * 8;
    }
    size_t brow[NT];
#pragma unroll
    for (int nt = 0; nt < NT; ++nt)
        brow[nt] = (size_t)(col0 + nt * 16 + ln15) * K + quad * 8;

    bf16x8 a0h[RG], a0l[RG], a1h[RG], a1l[RG];
    bf16x8 b0h[NT], b0l[NT], b1h[NT], b1l[NT];

#define LD_A(kc, AH, AL) { \
    _Pragma("unroll") \
    for (int g = 0; g < RG; ++g) { \
        AH[g] = *(const bf16x8*)(Ahi + arow[g] + (kc)); \
        AL[g] = *(const bf16x8*)(Alo + arow[g] + (kc)); \
    } }
#define LD_B(kc, BH, BL) { \
    _Pragma("unroll") \
    for (int nt = 0; nt < NT; ++nt) { \
        BH[nt] = *(const bf16x8*)(Whi + brow[nt] + (kc)); \
        BL[nt] = *(const bf16x8*)(Wlo + brow[nt] + (kc)); \
    } }
#define DO_MFMA(AH, AL, BH, BL) { \
    _Pragma("unroll") \
    for (int nt = 0; nt < NT; ++nt) { \
        _Pragma("unroll") \
        for (int g = 0; g < RG; ++g) { \
            acc[g][nt] = __builtin_amdgcn_mfma_f32_16x16x32_bf16(AH[g], BH[nt], acc[g][nt], 0, 0, 0); \
            acc[g][nt] = __builtin_amdgcn_mfma_f32_16x16x32_bf16(AH[g], BL[nt], acc[g][nt], 0, 0, 0); \
            acc[g][nt] = __builtin_amdgcn_mfma_f32_16x16x32_bf16(AL[g], BH[nt], acc[g][nt], 0, 0, 0); \
        } } }

    LD_A(0, a0h, a0l);
    LD_B(0, b0h, b0l);
    for (int s = 0; s < NK; s += 2) {
        LD_A((s + 1) * 32, a1h, a1l);
        LD_B((s + 1) * 32, b1h, b1l);
        DO_MFMA(a0h, a0l, b0h, b0l);
        if (s + 2 < NK) {
            LD_A((s + 2) * 32, a0h, a0l);
            LD_B((s + 2) * 32, b0h, b0l);
        }
        DO_MFMA(a1h, a1l, b1h, b1l);
    }
#undef LD_A
#undef LD_B
#undef DO_MFMA

    if (STATS) {
        if (t < 64) { st_lds[0][t] = 0.f; st_lds[1][t] = 0.f; }
        __syncthreads();
    }

    float bv[NT];
#pragma unroll
    for (int nt = 0; nt < NT; ++nt) bv[nt] = bias[col0 + nt * 16 + ln15];

    float s1[NT], s2[NT];
#pragma unroll
    for (int nt = 0; nt < NT; ++nt) { s1[nt] = 0.f; s2[nt] = 0.f; }

#pragma unroll
    for (int g = 0; g < RG; ++g)
#pragma unroll
        for (int r = 0; r < 4; ++r) {
            int row = row_base + g * 16 + quad * 4 + r;
            if (row < M) {
#pragma unroll
                for (int nt = 0; nt < NT; ++nt) {
                    float v = acc[g][nt][r] + bv[nt];
                    if (ACT == 1) v = gelu_exact(v);
                    size_t ci = (size_t)row * NC + col0 + nt * 16 + ln15;
                    if (OUTBF) {
                        __bf16 hh = (__bf16)v;
                        Chi[ci] = hh;
                        Clo[ci] = (__bf16)(v - (float)hh);
                    } else {
                        C[ci] = v;
                    }
                    if (STATS) { s1[nt] += v; s2[nt] += v * v; }
                }
            }
        }

    if (STATS) {
#pragma unroll
        for (int nt = 0; nt < NT; ++nt) {
            atomicAdd(&st_lds[0][nt * 16 + ln15], s1[nt]);
            atomicAdd(&st_lds[1][nt * 16 + ln15], s2[nt]);
        }
        __syncthreads();
        if (t < 64) {
            atomicAdd(&stats[col0 + t],      st_lds[0][t]);
            atomicAdd(&stats[HD + col0 + t], st_lds[1][t]);
        }
    }
}

// LayerNorm(+ReLU) over rows of 128, one wave per node; fp16 output
__global__ void ln_relu_k(const float* __restrict__ y, const float* __restrict__ gam,
                          const float* __restrict__ bet, _Float16* __restrict__ h16, int N)
{
    int lane = threadIdx.x & 63;
    int c0 = lane * 2;
    float2 g2 = *(const float2*)&gam[c0];
    float2 b2 = *(const float2*)&bet[c0];
    int wid = (blockIdx.x * blockDim.x + threadIdx.x) >> 6;
    int nw  = (gridDim.x * blockDim.x) >> 6;
    for (int n = wid; n < N; n += nw) {
        float2 v = *(const float2*)&y[(size_t)n * HD + c0];
        float s = v.x + v.y;
        float q = v.x * v.x + v.y * v.y;
#pragma unroll
        for (int o = 32; o > 0; o >>= 1) { s += __shfl_xor(s, o, 64); q += __shfl_xor(q, o, 64); }
        float mu  = s * (1.f / 128.f);
        float inv = rsqrtf(q * (1.f / 128.f) - mu * mu + LN_EPS);
        half2v r;
        r.x = (_Float16)fmaxf(fmaf((v.x - mu) * inv, g2.x, b2.x), 0.f);
        r.y = (_Float16)fmaxf(fmaf((v.y - mu) * inv, g2.y, b2.y), 0.f);
        *(half2v*)&h16[(size_t)n * HD + c0] = r;
    }
}

// ---------------- pull aggregation v8: fp16 attrs + v_dot2_f32_f16 ---------
// Structure = proven v5 (persistent waves, lane owns {2l,2l+1}, 64-edge LDS
// chunks). Attrs now fp16 (half the staging: 2 ds_read_b128/edge, 8KB LDS);
// edge-embed matvec via fdot2 (fp16 pair-dot, fp32 accumulate): 16 dot ops
// replace 32 fp32 FMAs. Weights pre-packed fp16 [c][k] by prep_k.
__launch_bounds__(256)
__global__ void pull8_k(const _Float16* __restrict__ h16, const int* __restrict__ rs,
                        const _Float16* __restrict__ attr16, const int2* __restrict__ sei,
                        const float* __restrict__ slv, const _Float16* __restrict__ Wg16,
                        const float* __restrict__ bg, const float* __restrict__ bet,
                        __bf16* __restrict__ Ahi, __bf16* __restrict__ Alo, int N)
{
    __shared__ _Float16 alds_all[4][64 * EDGED];   // 8 KB: per-wave attr staging
    const int t = threadIdx.x;
    const int lane = t & 63;
    const int wv = t >> 6;
    _Float16* alds = alds_all[wv];
    uint4* alds4 = (uint4*)alds;

    const int c0 = lane * 2;
    half2v w0p[8], w1p[8];
#pragma unroll
    for (int k = 0; k < 8; ++k) {
        w0p[k] = *(const half2v*)&Wg16[c0 * EDGED + 2 * k];
        w1p[k] = *(const half2v*)&Wg16[(c0 + 1) * EDGED + 2 * k];
    }
    const float2 bgv  = *(const float2*)&bg[c0];
    const float2 btv  = *(const float2*)&bet[c0];
    const float2 slvv = *(const float2*)&slv[c0];

    const int stride = gridDim.x << 2;
    for (int n = (blockIdx.x << 2) + wv; n < N; n += stride) {
        half2v hs = *(const half2v*)&h16[(size_t)n * HD + c0];
        float acc0 = (float)hs.x + slvv.x;
        float acc1 = (float)hs.y + slvv.y;

        const int beg = rs[n], end = rs[n + 1];
        for (int s0 = beg; s0 < end; s0 += 64) {
            int m = end - s0; if (m > 64) m = 64;
            int2 sv = make_int2(0, 0);
            if (lane < m) sv = sei[s0 + lane];
            // stage fp16 attrs: contiguous stream copy, 32B/edge
            const uint4* src4 = (const uint4*)(attr16 + (size_t)s0 * EDGED);
#pragma unroll
            for (int it = 0; it < 2; ++it) {
                int idx = (it << 6) + lane;
                if (idx < (m << 1)) alds4[idx] = src4[idx];
            }
            asm volatile("s_waitcnt lgkmcnt(0)" ::: "memory");

#define EDGE_BODY(JJ, IVJ, HVJ) { \
            HU ua, ub; \
            ua.v = *(const half8v*)&alds[(JJ) * EDGED]; \
            ub.v = *(const half8v*)&alds[(JJ) * EDGED + 8]; \
            float p0 = bgv.x, q0 = 0.f, p1 = bgv.y, q1 = 0.f; \
            p0 = __builtin_amdgcn_fdot2(ua.p[0], w0p[0], p0, false); \
            q0 = __builtin_amdgcn_fdot2(ua.p[1], w0p[1], q0, false); \
            p1 = __builtin_amdgcn_fdot2(ua.p[0], w1p[0], p1, false); \
            q1 = __builtin_amdgcn_fdot2(ua.p[1], w1p[1], q1, false); \
            p0 = __builtin_amdgcn_fdot2(ua.p[2], w0p[2], p0, false); \
            q0 = __builtin_amdgcn_fdot2(ua.p[3], w0p[3], q0, false); \
            p1 = __builtin_amdgcn_fdot2(ua.p[2], w1p[2], p1, false); \
            q1 = __builtin_amdgcn_fdot2(ua.p[3], w1p[3], q1, false); \
            p0 = __builtin_amdgcn_fdot2(ub.p[0], w0p[4], p0, false); \
            q0 = __builtin_amdgcn_fdot2(ub.p[1], w0p[5], q0, false); \
            p1 = __builtin_amdgcn_fdot2(ub.p[0], w1p[4], p1, false); \
            q1 = __builtin_amdgcn_fdot2(ub.p[1], w1p[5], q1, false); \
            p0 = __builtin_amdgcn_fdot2(ub.p[2], w0p[6], p0, false); \
            q0 = __builtin_amdgcn_fdot2(ub.p[3], w0p[7], q0, false); \
            p1 = __builtin_amdgcn_fdot2(ub.p[2], w1p[6], p1, false); \
            q1 = __builtin_amdgcn_fdot2(ub.p[3], w1p[7], q1, false); \
            acc0 += fmaxf(fmaf(p0 + q0, IVJ, btv.x), 0.f) + (float)HVJ.x; \
            acc1 += fmaxf(fmaf(p1 + q1, IVJ, btv.y), 0.f) + (float)HVJ.y; \
        }

            int j = 0;
            for (; j + 4 <= m; j += 4) {
                int s_0 = __shfl(sv.x, j,     64);
                int s_1 = __shfl(sv.x, j + 1, 64);
                int s_2 = __shfl(sv.x, j + 2, 64);
                int s_3 = __shfl(sv.x, j + 3, 64);
                float i0 = __int_as_float(__shfl(sv.y, j,     64));
                float i1 = __int_as_float(__shfl(sv.y, j + 1, 64));
                float i2 = __int_as_float(__shfl(sv.y, j + 2, 64));
                float i3 = __int_as_float(__shfl(sv.y, j + 3, 64));
                half2v h0 = *(const half2v*)&h16[(size_t)s_0 * HD + c0];
                half2v h1 = *(const half2v*)&h16[(size_t)s_1 * HD + c0];
                half2v h2 = *(const half2v*)&h16[(size_t)s_2 * HD + c0];
                half2v h3 = *(const half2v*)&h16[(size_t)s_3 * HD + c0];
                EDGE_BODY(j,     i0, h0);
                EDGE_BODY(j + 1, i1, h1);
                EDGE_BODY(j + 2, i2, h2);
                EDGE_BODY(j + 3, i3, h3);
            }
            for (; j < m; ++j) {
                int s_  = __shfl(sv.x, j, 64);
                float ij = __int_as_float(__shfl(sv.y, j, 64));
                half2v hj = *(const half2v*)&h16[(size_t)s_ * HD + c0];
                EDGE_BODY(j, ij, hj);
            }
#undef EDGE_BODY
        }
        __bf16 b0 = (__bf16)acc0, b1 = (__bf16)acc1;
        union { __bf16 b[2]; unsigned u; } ph, pl;
        ph.b[0] = b0;
        ph.b[1] = b1;
        pl.b[0] = (__bf16)(acc0 - (float)b0);
        pl.b[1] = (__bf16)(acc1 - (float)b1);
        *(unsigned*)&Ahi[(size_t)n * HD + c0] = ph.u;
        *(unsigned*)&Alo[(size_t)n * HD + c0] = pl.u;
    }
}

// BatchNorm apply from accumulated column sums; optional ReLU.
// out16 != null -> write fp16 (h for next layer); else fp32 to out32.
__global__ void bn_k(const float* __restrict__ hl, const float* __restrict__ stats,
                     const float* __restrict__ gam, const float* __restrict__ bet,
                     float* __restrict__ out32, _Float16* __restrict__ out16,
                     int total4, float invN, int relu)
{
    int idx = blockIdx.x * blockDim.x + threadIdx.x;
    if (idx < total4) {
        int c4 = idx & 31;
        float4 x  = ((const float4*)hl)[idx];
        float4 s1 = ((const float4*)stats)[c4];
        float4 s2 = ((const float4*)stats)[32 + c4];
        float4 g  = ((const float4*)gam)[c4];
        float4 b  = ((const float4*)bet)[c4];
        float4 r;
        {
            float m = s1.x * invN; float v = s2.x * invN - m * m;
            r.x = fmaf((x.x - m) * rsqrtf(v + LN_EPS), g.x, b.x);
        }
        {
            float m = s1.y * invN; float v = s2.y * invN - m * m;
            r.y = fmaf((x.y - m) * rsqrtf(v + LN_EPS), g.y, b.y);
        }
        {
            float m = s1.z * invN; float v = s2.z * invN - m * m;
            r.z = fmaf((x.z - m) * rsqrtf(v + LN_EPS), g.z, b.z);
        }
        {
            float m = s1.w * invN; float v = s2.w * invN - m * m;
            r.w = fmaf((x.w - m) * rsqrtf(v + LN_EPS), g.w, b.w);
        }
        if (relu) {
            r.x = fmaxf(r.x, 0.f); r.y = fmaxf(r.y, 0.f);
            r.z = fmaxf(r.z, 0.f); r.w = fmaxf(r.w, 0.f);
        }
        if (out16) {
            half4v o;
            o.x = (_Float16)r.x; o.y = (_Float16)r.y;
            o.z = (_Float16)r.z; o.w = (_Float16)r.w;
            *(half4v*)&out16[(size_t)idx * 4] = o;
        } else {
            ((float4*)out32)[idx] = r;
        }
    }
}

extern "C" void kernel_launch(void* const* d_in, const int* in_sizes, int n_in,
                              void* d_out, int out_size, void* d_ws, size_t ws_size,
                              hipStream_t stream)
{
    const float* x       = (const float*)d_in[0];
    const int*   ei      = (const int*)d_in[1];
    const float* eattr   = (const float*)d_in[2];
    const float* node_W  = (const float*)d_in[3];
    const float* node_b  = (const float*)d_in[4];
    const float* node_g  = (const float*)d_in[5];
    const float* node_be = (const float*)d_in[6];
    const float* edge_W  = (const float*)d_in[7];
    const float* edge_b  = (const float*)d_in[8];
    const float* edge_g  = (const float*)d_in[9];
    const float* edge_be = (const float*)d_in[10];
    const float* sl_attr = (const float*)d_in[11];
    const float* W1      = (const float*)d_in[12];
    const float* b1      = (const float*)d_in[13];
    const float* W2      = (const float*)d_in[14];
    const float* b2      = (const float*)d_in[15];
    const float* bn_g    = (const float*)d_in[16];
    const float* bn_b    = (const float*)d_in[17];

    const int N = in_sizes[0] / NODED;
    const int E = in_sizes[1] / 2;

    // explicit 16B-aligned workspace layout
    char* base = (char*)d_ws;
    size_t off = 0;
    auto take = [&](size_t nbytes) -> void* {
        void* p = base + off;
        off = (off + nbytes + 15) & ~(size_t)15;
        return p;
    };
    _Float16* h16  = (_Float16*)take((size_t)N * HD * 2); // node features (fp16)
    float*  z      = (float*)take((size_t)N * HD * 4);     // node-embed pre-LN (fp32)
    __bf16* aghi   = (__bf16*)take((size_t)N * HD * 2);    // aggr bf16 hi
    __bf16* aglo   = (__bf16*)take((size_t)N * HD * 2);
    __bf16* zhi    = (__bf16*)take((size_t)N * 256 * 2);   // mlp1 out bf16 hi
    __bf16* zlo    = (__bf16*)take((size_t)N * 256 * 2);
    __bf16* xhi    = (__bf16*)take((size_t)N * NODED * 2);
    __bf16* xlo    = (__bf16*)take((size_t)N * NODED * 2);
    float*  slv3   = (float*)take(3 * HD * 4);
    float*  stats  = (float*)take(3 * 256 * 4);
    int*    cnt    = (int*)take((size_t)N * 4);
    int*    cursor = (int*)take((size_t)N * 4);
    int*    bsum   = (int*)take(256 * 4);
    int*    boff   = (int*)take(256 * 4);
    int*    rs     = (int*)take(((size_t)N + 2) * 4);
    int2*   es     = (int2*)take((size_t)E * 8);
    int2*   sei    = (int2*)take((size_t)3 * E * 8);       // (src, inv-std bits)
    _Float16* attr16 = (_Float16*)take((size_t)E * EDGED * 2); // slot-permuted fp16 attrs
    _Float16* Wg16_3 = (_Float16*)take(3 * 2048 * 2);      // fp16 edge weights [c][k]
    float*  bg3    = (float*)take(3 * HD * 4);
    float*  M3     = (float*)take(3 * 256 * 4);
    float*  v3     = (float*)take(3 * 16 * 4);
    float*  s03    = (float*)take(4 * 4);
    __bf16* nWhi   = (__bf16*)take((size_t)HD * NODED * 2);
    __bf16* nWlo   = (__bf16*)take((size_t)HD * NODED * 2);
    __bf16* W1hi   = (__bf16*)take((size_t)3 * 256 * HD * 2);
    __bf16* W1lo   = (__bf16*)take((size_t)3 * 256 * HD * 2);
    __bf16* W2hi   = (__bf16*)take((size_t)3 * HD * 256 * 2);
    __bf16* W2lo   = (__bf16*)take((size_t)3 * HD * 256 * 2);

    // bf16 hi/lo splits: weights ([N][K] row-major already) and x
    wconv_k<<<(HD * NODED + 255) / 256, 256, 0, stream>>>(node_W, nWhi, nWlo, HD * NODED);
    wconv_k<<<(3 * 256 * HD + 255) / 256, 256, 0, stream>>>(W1, W1hi, W1lo, 3 * 256 * HD);
    wconv_k<<<(3 * 256 * HD + 255) / 256, 256, 0, stream>>>(W2, W2hi, W2lo, 3 * 256 * HD);
    wconv_k<<<((int)((size_t)N * NODED + 255) / 256), 256, 0, stream>>>(x, xhi, xlo, N * NODED);

    // edge-LN precompute + self-loop embed + fp16 weights (all 3 layers)
    prep_k<<<3, 256, 0, stream>>>(edge_W, edge_b, edge_g, edge_be, sl_attr,
                                  Wg16_3, bg3, M3, v3, s03, slv3);

    // ---- CSR build ----
    const int eblocks = (E + 255) / 256;
    const int nblocks = (N + 255) / 256;
    hipMemsetAsync(cnt, 0, (size_t)N * sizeof(int), stream);
    hist_k<<<eblocks, 256, 0, stream>>>(ei, cnt, E);
    scan1_k<<<nblocks, 256, 0, stream>>>(cnt, rs, bsum, N);
    scan2_k<<<1, 256, 0, stream>>>(bsum, boff, nblocks);
    scan3_k<<<nblocks, 256, 0, stream>>>(rs, cursor, boff, N, E);
    scatter_k<<<eblocks, 256, 0, stream>>>(ei, cursor, es, E);

    // per-slot (src, inv-std) for all 3 layers + permuted fp16 attr stream
    einv_k<<<eblocks, 256, 0, stream>>>(es, eattr, M3, v3, s03, sei, attr16, E);

    const int total4  = N * (HD / 4);
    const int vblocks = (total4 + 255) / 256;
    const int gb128   = (N + 127) / 128;
    int pgrid = (N + 3) / 4;
    if (pgrid > 2048) pgrid = 2048;           // persistent: 8192 waves

    // node embed: Linear (MFMA) -> LN -> ReLU
    mgemm_k<NODED, HD, 0, 0, 0><<<dim3(gb128, 2), 256, 0, stream>>>(
        xhi, xlo, nWhi, nWlo, node_b, z, nullptr, nullptr, N, nullptr);
    ln_relu_k<<<(N + 3) / 4, 256, 0, stream>>>(z, node_g, node_be, h16, N);

    hipMemsetAsync(stats, 0, 3 * 256 * sizeof(float), stream);

    for (int l = 0; l < 3; ++l) {
        pull8_k<<<pgrid, 256, 0, stream>>>(h16, rs, attr16, sei + (size_t)l * E,
                                           slv3 + l * HD, Wg16_3 + (size_t)l * 2048,
                                           bg3 + l * HD, edge_be + l * HD,
                                           aghi, aglo, N);

        mgemm_k<HD, 256, 1, 0, 1><<<dim3(gb128, 4), 256, 0, stream>>>(
            aghi, aglo, W1hi + (size_t)l * 256 * HD, W1lo + (size_t)l * 256 * HD,
            b1 + l * 256, nullptr, zhi, zlo, N, nullptr);

        mgemm_k<256, HD, 0, 1, 0><<<dim3(gb128, 2), 256, 0, stream>>>(
            zhi, zlo, W2hi + (size_t)l * HD * 256, W2lo + (size_t)l * HD * 256,
            b2 + l * HD, (float*)d_out, nullptr, nullptr, N, stats + l * 256);

        bn_k<<<vblocks, 256, 0, stream>>>((const float*)d_out, stats + l * 256,
                                          bn_g + l * HD, bn_b + l * HD,
                                          (float*)d_out, (l < 2) ? h16 : nullptr,
                                          total4, 1.f / N, (l < 2) ? 1 : 0);
    }
}

// Round 7
// 871.954 us; speedup vs baseline: 1.4737x; 1.0131x over previous
//
#include <hip/hip_runtime.h>
#include <cstdint>
#include <cstddef>

#define HD 128
#define EDGED 16
#define NODED 64
#define LN_EPS 1e-5f

typedef __bf16 bf16x8 __attribute__((ext_vector_type(8)));
typedef float  f32x4  __attribute__((ext_vector_type(4)));
typedef _Float16 half2v __attribute__((ext_vector_type(2)));
typedef _Float16 half4v __attribute__((ext_vector_type(4)));
typedef _Float16 half8v __attribute__((ext_vector_type(8)));

union HU { half8v v; half2v p[4]; };

__device__ __forceinline__ float gelu_exact(float x) {
    return 0.5f * x * (1.0f + erff(x * 0.7071067811865475f));
}

__device__ __forceinline__ float hi16_to_f(int bits) {
    union { unsigned short u; _Float16 h; } c;
    c.u = (unsigned short)((unsigned)bits >> 16);
    return (float)c.h;
}

// fp32 -> bf16 hi/lo split (a ~= hi + lo, lo captures the rounding residual)
__global__ void wconv_k(const float* __restrict__ in, __bf16* __restrict__ hi,
                        __bf16* __restrict__ lo, int n) {
    int i = blockIdx.x * blockDim.x + threadIdx.x;
    if (i < n) {
        float v = in[i];
        __bf16 h = (__bf16)v;
        hi[i] = h;
        lo[i] = (__bf16)(v - (float)h);
    }
}

// fp32 -> fp16 hi/lo split
__global__ void wconv16_k(const float* __restrict__ in, _Float16* __restrict__ hi,
                          _Float16* __restrict__ lo, int n) {
    int i = blockIdx.x * blockDim.x + threadIdx.x;
    if (i < n) {
        float v = in[i];
        _Float16 h = (_Float16)v;
        hi[i] = h;
        lo[i] = (_Float16)(v - (float)h);
    }
}

// ---------------- CSR build ----------------

__global__ void hist_k(const int* __restrict__ ei, int* __restrict__ cnt, int E) {
    int e = blockIdx.x * blockDim.x + threadIdx.x;
    if (e < E) atomicAdd(&cnt[ei[E + e]], 1);
}

__global__ void scan1_k(const int* __restrict__ in, int* __restrict__ out,
                        int* __restrict__ bsum, int n) {
    __shared__ int lds[256];
    int t = threadIdx.x;
    int i = blockIdx.x * 256 + t;
    int v = (i < n) ? in[i] : 0;
    lds[t] = v;
    __syncthreads();
#pragma unroll
    for (int o = 1; o < 256; o <<= 1) {
        int u = (t >= o) ? lds[t - o] : 0;
        __syncthreads();
        lds[t] += u;
        __syncthreads();
    }
    if (i < n) out[i] = lds[t] - v;
    if (t == 255) bsum[blockIdx.x] = lds[255];
}

__global__ void scan2_k(const int* __restrict__ bsum, int* __restrict__ boff, int nb) {
    __shared__ int lds[256];
    int t = threadIdx.x;
    int v = (t < nb) ? bsum[t] : 0;
    lds[t] = v;
    __syncthreads();
#pragma unroll
    for (int o = 1; o < 256; o <<= 1) {
        int u = (t >= o) ? lds[t - o] : 0;
        __syncthreads();
        lds[t] += u;
        __syncthreads();
    }
    if (t < nb) boff[t] = lds[t] - v;
}

// adds block offsets; also emits the scatter cursor copy (saves a d2d memcpy)
__global__ void scan3_k(int* __restrict__ rs, int* __restrict__ cursor,
                        const int* __restrict__ boff, int n, int E) {
    int i = blockIdx.x * 256 + threadIdx.x;
    if (i < n) {
        int v = rs[i] + boff[blockIdx.x];
        rs[i] = v;
        cursor[i] = v;
    }
    if (i == 0) rs[n] = E;
}

__global__ void scatter_k(const int* __restrict__ ei, int* __restrict__ cursor,
                          int2* __restrict__ es, int E) {
    int e = blockIdx.x * blockDim.x + threadIdx.x;
    if (e < E) {
        int dst = ei[E + e];
        int slot = atomicAdd(&cursor[dst], 1);
        es[slot] = make_int2(ei[e], e);
    }
}

// ---------------- edge-LN precompute (+ fused self-loop embed) ----------------
// Per layer l: wm[k]=mean_c W[c][k]; bm=mean(b); Wp=W-wm; bp=b-bm.
// Wg16[c][k] = (fp16)(Wp[c][k]*g[c]); bg[c] = bp[c]*g[c]
// M[k][j] = sum_c Wp[c][k]*Wp[c][j]; v[k]=2*sum_c Wp[c][k]*bp[c]; s0=sum bp^2
// Tail: embeds the learned self-loop attr for this layer into slv3[l].
__global__ void prep_k(const float* __restrict__ edge_W, const float* __restrict__ edge_b,
                       const float* __restrict__ edge_g, const float* __restrict__ edge_be,
                       const float* __restrict__ sl_attr, _Float16* __restrict__ Wg16_3,
                       float* __restrict__ bg3, float* __restrict__ M3,
                       float* __restrict__ v3, float* __restrict__ s03,
                       float* __restrict__ slv3)
{
    const int l = blockIdx.x;
    const float* W = edge_W + (size_t)l * HD * EDGED;
    const float* b = edge_b + l * HD;
    const float* g = edge_g + l * HD;
    __shared__ float Wp[HD * EDGED];
    __shared__ float bp[HD];
    __shared__ float wm[EDGED];
    __shared__ float Msh[256];
    __shared__ float vsh[EDGED];
    __shared__ float ash[EDGED];
    __shared__ float bmS, s0sh;
    const int t = threadIdx.x;
#pragma unroll
    for (int m = 0; m < 8; ++m) Wp[m * 256 + t] = W[m * 256 + t];
    __syncthreads();
    if (t < EDGED) {
        float s = 0.f;
        for (int c = 0; c < HD; ++c) s += Wp[c * EDGED + t];
        wm[t] = s * (1.f / HD);
    } else if (t == EDGED) {
        float s = 0.f;
        for (int c = 0; c < HD; ++c) s += b[c];
        bmS = s * (1.f / HD);
    }
    __syncthreads();
    if (t < HD) bp[t] = b[t] - bmS;
    __syncthreads();
#pragma unroll
    for (int m = 0; m < 8; ++m) {
        int idx = m * 256 + t;
        int c = idx >> 4, k = idx & 15;
        float val = Wp[idx] - wm[k];
        Wp[idx] = val;
        Wg16_3[(size_t)l * 2048 + idx] = (_Float16)(val * g[c]);   // [c][k] layout
    }
    if (t < HD) bg3[l * HD + t] = bp[t] * g[t];
    __syncthreads();
    {
        int k = t >> 4, j = t & 15;
        float s = 0.f;
        for (int c = 0; c < HD; ++c) s += Wp[c * EDGED + k] * Wp[c * EDGED + j];
        Msh[t] = s;
        M3[l * 256 + t] = s;
    }
    if (t < EDGED) {
        float s = 0.f;
        for (int c = 0; c < HD; ++c) s += Wp[c * EDGED + t] * bp[c];
        vsh[t] = 2.f * s;
        v3[l * EDGED + t] = 2.f * s;
        ash[t] = sl_attr[l * EDGED + t];
    } else if (t == EDGED) {
        float s = 0.f;
        for (int c = 0; c < HD; ++c) s += bp[c] * bp[c];
        s0sh = s;
        s03[l] = s;
    }
    __syncthreads();
    // self-loop embed: out_c = ((Wp.a)*g + bg)*inv + bet, relu
    if (t < HD) {
        float q = s0sh;
#pragma unroll
        for (int k = 0; k < EDGED; ++k) {
            float tk = vsh[k];
#pragma unroll
            for (int j = 0; j < EDGED; ++j) tk = fmaf(Msh[k * 16 + j], ash[j], tk);
            q = fmaf(ash[k], tk, q);
        }
        float inv = rsqrtf(q * (1.f / HD) + LN_EPS);
        float y = 0.f;
#pragma unroll
        for (int k = 0; k < EDGED; ++k) y = fmaf(Wp[t * EDGED + k], ash[k], y);
        slv3[l * HD + t] = fmaxf(fmaf(fmaf(y, g[t], bg3[l * HD + t]), inv, edge_be[l * HD + t]), 0.f);
    }
}

// Per CSR slot: gather attr row once; emit PACKED meta per layer:
// low 16 bits = src node id (N < 65536), high 16 bits = fp16 inv-std.
// Also emits the attr row PERMUTED into slot order as fp16 (attr16).
__launch_bounds__(256)
__global__ void einv_k(const int2* __restrict__ es, const float* __restrict__ eattr,
                       const float* __restrict__ M3, const float* __restrict__ v3,
                       const float* __restrict__ s03, unsigned* __restrict__ sei,
                       _Float16* __restrict__ attr16, int E)
{
    __shared__ float Ms[3 * 256];
    __shared__ float vs[3 * 16];
    __shared__ float s0s[4];
    const int t = threadIdx.x;
    for (int i = t; i < 768; i += 256) Ms[i] = M3[i];
    if (t < 48) vs[t] = v3[t];
    if (t < 3) s0s[t] = s03[t];
    __syncthreads();
    int slot = blockIdx.x * 256 + t;
    if (slot >= E) return;
    int2 se = es[slot];
    const float4* ap = (const float4*)(eattr + (size_t)se.y * EDGED);
    float4 A0 = ap[0], A1 = ap[1], A2 = ap[2], A3 = ap[3];
    float a[16] = {A0.x, A0.y, A0.z, A0.w, A1.x, A1.y, A1.z, A1.w,
                   A2.x, A2.y, A2.z, A2.w, A3.x, A3.y, A3.z, A3.w};
    {
        half8v o0, o1;
#pragma unroll
        for (int i = 0; i < 8; ++i) { o0[i] = (_Float16)a[i]; o1[i] = (_Float16)a[8 + i]; }
        _Float16* op = attr16 + (size_t)slot * EDGED;
        *(half8v*)&op[0] = o0;
        *(half8v*)&op[8] = o1;
    }
#pragma unroll
    for (int l = 0; l < 3; ++l) {
        float q = s0s[l];
#pragma unroll
        for (int k = 0; k < 16; ++k) {
            const float* Mr = &Ms[l * 256 + k * 16];
            float tk = vs[l * 16 + k];
#pragma unroll
            for (int j = 0; j < 16; ++j) tk = fmaf(Mr[j], a[j], tk);
            q = fmaf(a[k], tk, q);
        }
        float iv = rsqrtf(q * (1.f / HD) + LN_EPS);
        union { _Float16 h; unsigned short u; } cv;
        cv.h = (_Float16)iv;
        sei[(size_t)l * E + slot] = ((unsigned)se.x & 0xFFFFu) | ((unsigned)cv.u << 16);
    }
}

// ---------------- MFMA GEMM v3 ---------------------------------------------
// AMODE 0: A bf16 hi/lo + W bf16 hi/lo (3 MFMA, ~fp32 accuracy)
// AMODE 1: A fp16 single + W fp16 hi/lo (2 MFMA f16, ~2.4e-4 rel on A)
// OUTMODE 0: fp32 C; 2: fp16 single (Co1)
template<int K, int NC, int ACT, int STATS, int AMODE, int OUTMODE>
__launch_bounds__(256)
__global__ void mgemm_k(const void* __restrict__ Ap1, const void* __restrict__ Ap2,
                        const void* __restrict__ Wp1, const void* __restrict__ Wp2,
                        const float* __restrict__ bias, float* __restrict__ C,
                        void* __restrict__ Co1, int M, float* __restrict__ stats)
{
    constexpr int RG = 2;
    constexpr int NT = 4;
    constexpr int NK = K / 32;
    __shared__ float st_lds[2][64];

    const int t    = threadIdx.x;
    const int lane = t & 63;
    const int wv   = t >> 6;
    const int ln15 = lane & 15;
    const int quad = lane >> 4;
    const int row_base = blockIdx.x * 128 + wv * 32;
    const int col0 = blockIdx.y * 64;

    f32x4 acc[RG][NT];
#pragma unroll
    for (int g = 0; g < RG; ++g)
#pragma unroll
        for (int nt = 0; nt < NT; ++nt)
#pragma unroll
            for (int r = 0; r < 4; ++r) acc[g][nt][r] = 0.f;

    size_t arow[RG];
#pragma unroll
    for (int g = 0; g < RG; ++g) {
        int row = row_base + g * 16 + ln15;
        row = row < M ? row : M - 1;          // clamp: junk values, store masked
        arow[g] = (size_t)row * K + quad * 8;
    }
    size_t brow[NT];
#pragma unroll
    for (int nt = 0; nt < NT; ++nt)
        brow[nt] = (size_t)(col0 + nt * 16 + ln15) * K + quad * 8;

    if constexpr (AMODE == 0) {
        const __bf16* Ahi = (const __bf16*)Ap1;
        const __bf16* Alo = (const __bf16*)Ap2;
        const __bf16* Whi = (const __bf16*)Wp1;
        const __bf16* Wlo = (const __bf16*)Wp2;
        bf16x8 a0h[RG], a0l[RG], a1h[RG], a1l[RG];
        bf16x8 b0h[NT], b0l[NT], b1h[NT], b1l[NT];

#define LD_A(kc, AH, AL) { \
    _Pragma("unroll") \
    for (int g = 0; g < RG; ++g) { \
        AH[g] = *(const bf16x8*)(Ahi + arow[g] + (kc)); \
        AL[g] = *(const bf16x8*)(Alo + arow[g] + (kc)); \
    } }
#define LD_B(kc, BH, BL) { \
    _Pragma("unroll") \
    for (int nt = 0; nt < NT; ++nt) { \
        BH[nt] = *(const bf16x8*)(Whi + brow[nt] + (kc)); \
        BL[nt] = *(const bf16x8*)(Wlo + brow[nt] + (kc)); \
    } }
#define DO_MFMA(AH, AL, BH, BL) { \
    _Pragma("unroll") \
    for (int nt = 0; nt < NT; ++nt) { \
        _Pragma("unroll") \
        for (int g = 0; g < RG; ++g) { \
            acc[g][nt] = __builtin_amdgcn_mfma_f32_16x16x32_bf16(AH[g], BH[nt], acc[g][nt], 0, 0, 0); \
            acc[g][nt] = __builtin_amdgcn_mfma_f32_16x16x32_bf16(AH[g], BL[nt], acc[g][nt], 0, 0, 0); \
            acc[g][nt] = __builtin_amdgcn_mfma_f32_16x16x32_bf16(AL[g], BH[nt], acc[g][nt], 0, 0, 0); \
        } } }

        LD_A(0, a0h, a0l);
        LD_B(0, b0h, b0l);
        for (int s = 0; s < NK; s += 2) {
            LD_A((s + 1) * 32, a1h, a1l);
            LD_B((s + 1) * 32, b1h, b1l);
            DO_MFMA(a0h, a0l, b0h, b0l);
            if (s + 2 < NK) {
                LD_A((s + 2) * 32, a0h, a0l);
                LD_B((s + 2) * 32, b0h, b0l);
            }
            DO_MFMA(a1h, a1l, b1h, b1l);
        }
#undef LD_A
#undef LD_B
#undef DO_MFMA
    } else {
        const _Float16* Af = (const _Float16*)Ap1;
        const _Float16* Wh = (const _Float16*)Wp1;
        const _Float16* Wl = (const _Float16*)Wp2;
        half8v a0[RG], a1[RG];
        half8v b0h[NT], b0l[NT], b1h[NT], b1l[NT];

#define LD_A16(kc, A) { \
    _Pragma("unroll") \
    for (int g = 0; g < RG; ++g) A[g] = *(const half8v*)(Af + arow[g] + (kc)); }
#define LD_B16(kc, BH, BL) { \
    _Pragma("unroll") \
    for (int nt = 0; nt < NT; ++nt) { \
        BH[nt] = *(const half8v*)(Wh + brow[nt] + (kc)); \
        BL[nt] = *(const half8v*)(Wl + brow[nt] + (kc)); \
    } }
#define DO_MFMA16(A, BH, BL) { \
    _Pragma("unroll") \
    for (int nt = 0; nt < NT; ++nt) { \
        _Pragma("unroll") \
        for (int g = 0; g < RG; ++g) { \
            acc[g][nt] = __builtin_amdgcn_mfma_f32_16x16x32_f16(A[g], BH[nt], acc[g][nt], 0, 0, 0); \
            acc[g][nt] = __builtin_amdgcn_mfma_f32_16x16x32_f16(A[g], BL[nt], acc[g][nt], 0, 0, 0); \
        } } }

        LD_A16(0, a0);
        LD_B16(0, b0h, b0l);
        for (int s = 0; s < NK; s += 2) {
            LD_A16((s + 1) * 32, a1);
            LD_B16((s + 1) * 32, b1h, b1l);
            DO_MFMA16(a0, b0h, b0l);
            if (s + 2 < NK) {
                LD_A16((s + 2) * 32, a0);
                LD_B16((s + 2) * 32, b0h, b0l);
            }
            DO_MFMA16(a1, b1h, b1l);
        }
#undef LD_A16
#undef LD_B16
#undef DO_MFMA16
    }

    if (STATS) {
        if (t < 64) { st_lds[0][t] = 0.f; st_lds[1][t] = 0.f; }
        __syncthreads();
    }

    float bv[NT];
#pragma unroll
    for (int nt = 0; nt < NT; ++nt) bv[nt] = bias[col0 + nt * 16 + ln15];

    float s1[NT], s2[NT];
#pragma unroll
    for (int nt = 0; nt < NT; ++nt) { s1[nt] = 0.f; s2[nt] = 0.f; }

#pragma unroll
    for (int g = 0; g < RG; ++g)
#pragma unroll
        for (int r = 0; r < 4; ++r) {
            int row = row_base + g * 16 + quad * 4 + r;
            if (row < M) {
#pragma unroll
                for (int nt = 0; nt < NT; ++nt) {
                    float v = acc[g][nt][r] + bv[nt];
                    if (ACT == 1) v = gelu_exact(v);
                    size_t ci = (size_t)row * NC + col0 + nt * 16 + ln15;
                    if (OUTMODE == 2) {
                        ((_Float16*)Co1)[ci] = (_Float16)v;
                    } else {
                        C[ci] = v;
                    }
                    if (STATS) { s1[nt] += v; s2[nt] += v * v; }
                }
            }
        }

    if (STATS) {
#pragma unroll
        for (int nt = 0; nt < NT; ++nt) {
            atomicAdd(&st_lds[0][nt * 16 + ln15], s1[nt]);
            atomicAdd(&st_lds[1][nt * 16 + ln15], s2[nt]);
        }
        __syncthreads();
        if (t < 64) {
            atomicAdd(&stats[col0 + t],      st_lds[0][t]);
            atomicAdd(&stats[HD + col0 + t], st_lds[1][t]);
        }
    }
}

// LayerNorm(+ReLU) over rows of 128, one wave per node; fp16 output
__global__ void ln_relu_k(const float* __restrict__ y, const float* __restrict__ gam,
                          const float* __restrict__ bet, _Float16* __restrict__ h16, int N)
{
    int lane = threadIdx.x & 63;
    int c0 = lane * 2;
    float2 g2 = *(const float2*)&gam[c0];
    float2 b2 = *(const float2*)&bet[c0];
    int wid = (blockIdx.x * blockDim.x + threadIdx.x) >> 6;
    int nw  = (gridDim.x * blockDim.x) >> 6;
    for (int n = wid; n < N; n += nw) {
        float2 v = *(const float2*)&y[(size_t)n * HD + c0];
        float s = v.x + v.y;
        float q = v.x * v.x + v.y * v.y;
#pragma unroll
        for (int o = 32; o > 0; o >>= 1) { s += __shfl_xor(s, o, 64); q += __shfl_xor(q, o, 64); }
        float mu  = s * (1.f / 128.f);
        float inv = rsqrtf(q * (1.f / 128.f) - mu * mu + LN_EPS);
        half2v r;
        r.x = (_Float16)fmaxf(fmaf((v.x - mu) * inv, g2.x, b2.x), 0.f);
        r.y = (_Float16)fmaxf(fmaf((v.y - mu) * inv, g2.y, b2.y), 0.f);
        *(half2v*)&h16[(size_t)n * HD + c0] = r;
    }
}

// ---------------- pull aggregation v9: packed meta + fdot2 -----------------
// = verified v8 structure with sei packed to 4B (src low 16, fp16 iv high 16):
// one dword meta load + ONE shfl per edge (was int2 + 2 shfl).
__launch_bounds__(256)
__global__ void pull9_k(const _Float16* __restrict__ h16, const int* __restrict__ rs,
                        const _Float16* __restrict__ attr16, const unsigned* __restrict__ sei,
                        const float* __restrict__ slv, const _Float16* __restrict__ Wg16,
                        const float* __restrict__ bg, const float* __restrict__ bet,
                        __bf16* __restrict__ Ahi, __bf16* __restrict__ Alo, int N)
{
    __shared__ _Float16 alds_all[4][64 * EDGED];   // 8 KB: per-wave attr staging
    const int t = threadIdx.x;
    const int lane = t & 63;
    const int wv = t >> 6;
    _Float16* alds = alds_all[wv];
    uint4* alds4 = (uint4*)alds;

    const int c0 = lane * 2;
    half2v w0p[8], w1p[8];
#pragma unroll
    for (int k = 0; k < 8; ++k) {
        w0p[k] = *(const half2v*)&Wg16[c0 * EDGED + 2 * k];
        w1p[k] = *(const half2v*)&Wg16[(c0 + 1) * EDGED + 2 * k];
    }
    const float2 bgv  = *(const float2*)&bg[c0];
    const float2 btv  = *(const float2*)&bet[c0];
    const float2 slvv = *(const float2*)&slv[c0];

    const int stride = gridDim.x << 2;
    for (int n = (blockIdx.x << 2) + wv; n < N; n += stride) {
        half2v hs = *(const half2v*)&h16[(size_t)n * HD + c0];
        float acc0 = (float)hs.x + slvv.x;
        float acc1 = (float)hs.y + slvv.y;

        const int beg = rs[n], end = rs[n + 1];
        for (int s0 = beg; s0 < end; s0 += 64) {
            int m = end - s0; if (m > 64) m = 64;
            int sv = 0;
            if (lane < m) sv = (int)sei[s0 + lane];
            // stage fp16 attrs: contiguous stream copy, 32B/edge
            const uint4* src4 = (const uint4*)(attr16 + (size_t)s0 * EDGED);
#pragma unroll
            for (int it = 0; it < 2; ++it) {
                int idx = (it << 6) + lane;
                if (idx < (m << 1)) alds4[idx] = src4[idx];
            }
            asm volatile("s_waitcnt lgkmcnt(0)" ::: "memory");

#define EDGE_BODY(JJ, IVJ, HVJ) { \
            HU ua, ub; \
            ua.v = *(const half8v*)&alds[(JJ) * EDGED]; \
            ub.v = *(const half8v*)&alds[(JJ) * EDGED + 8]; \
            float p0 = bgv.x, q0 = 0.f, p1 = bgv.y, q1 = 0.f; \
            p0 = __builtin_amdgcn_fdot2(ua.p[0], w0p[0], p0, false); \
            q0 = __builtin_amdgcn_fdot2(ua.p[1], w0p[1], q0, false); \
            p1 = __builtin_amdgcn_fdot2(ua.p[0], w1p[0], p1, false); \
            q1 = __builtin_amdgcn_fdot2(ua.p[1], w1p[1], q1, false); \
            p0 = __builtin_amdgcn_fdot2(ua.p[2], w0p[2], p0, false); \
            q0 = __builtin_amdgcn_fdot2(ua.p[3], w0p[3], q0, false); \
            p1 = __builtin_amdgcn_fdot2(ua.p[2], w1p[2], p1, false); \
            q1 = __builtin_amdgcn_fdot2(ua.p[3], w1p[3], q1, false); \
            p0 = __builtin_amdgcn_fdot2(ub.p[0], w0p[4], p0, false); \
            q0 = __builtin_amdgcn_fdot2(ub.p[1], w0p[5], q0, false); \
            p1 = __builtin_amdgcn_fdot2(ub.p[0], w1p[4], p1, false); \
            q1 = __builtin_amdgcn_fdot2(ub.p[1], w1p[5], q1, false); \
            p0 = __builtin_amdgcn_fdot2(ub.p[2], w0p[6], p0, false); \
            q0 = __builtin_amdgcn_fdot2(ub.p[3], w0p[7], q0, false); \
            p1 = __builtin_amdgcn_fdot2(ub.p[2], w1p[6], p1, false); \
            q1 = __builtin_amdgcn_fdot2(ub.p[3], w1p[7], q1, false); \
            acc0 += fmaxf(fmaf(p0 + q0, IVJ, btv.x), 0.f) + (float)HVJ.x; \
            acc1 += fmaxf(fmaf(p1 + q1, IVJ, btv.y), 0.f) + (float)HVJ.y; \
        }

            int j = 0;
            for (; j + 4 <= m; j += 4) {
                int v0 = __shfl(sv, j,     64);
                int v1 = __shfl(sv, j + 1, 64);
                int v2 = __shfl(sv, j + 2, 64);
                int v3 = __shfl(sv, j + 3, 64);
                int s_0 = v0 & 0xFFFF, s_1 = v1 & 0xFFFF;
                int s_2 = v2 & 0xFFFF, s_3 = v3 & 0xFFFF;
                float i0 = hi16_to_f(v0);
                float i1 = hi16_to_f(v1);
                float i2 = hi16_to_f(v2);
                float i3 = hi16_to_f(v3);
                half2v h0 = *(const half2v*)&h16[(size_t)s_0 * HD + c0];
                half2v h1 = *(const half2v*)&h16[(size_t)s_1 * HD + c0];
                half2v h2 = *(const half2v*)&h16[(size_t)s_2 * HD + c0];
                half2v h3 = *(const half2v*)&h16[(size_t)s_3 * HD + c0];
                EDGE_BODY(j,     i0, h0);
                EDGE_BODY(j + 1, i1, h1);
                EDGE_BODY(j + 2, i2, h2);
                EDGE_BODY(j + 3, i3, h3);
            }
            for (; j < m; ++j) {
                int vj = __shfl(sv, j, 64);
                int s_ = vj & 0xFFFF;
                float ij = hi16_to_f(vj);
                half2v hj = *(const half2v*)&h16[(size_t)s_ * HD + c0];
                EDGE_BODY(j, ij, hj);
            }
#undef EDGE_BODY
        }
        __bf16 b0 = (__bf16)acc0, b1 = (__bf16)acc1;
        union { __bf16 b[2]; unsigned u; } ph, pl;
        ph.b[0] = b0;
        ph.b[1] = b1;
        pl.b[0] = (__bf16)(acc0 - (float)b0);
        pl.b[1] = (__bf16)(acc1 - (float)b1);
        *(unsigned*)&Ahi[(size_t)n * HD + c0] = ph.u;
        *(unsigned*)&Alo[(size_t)n * HD + c0] = pl.u;
    }
}

// BatchNorm apply from accumulated column sums; optional ReLU.
// out16 != null -> write fp16 (h for next layer); else fp32 to out32.
__global__ void bn_k(const float* __restrict__ hl, const float* __restrict__ stats,
                     const float* __restrict__ gam, const float* __restrict__ bet,
                     float* __restrict__ out32, _Float16* __restrict__ out16,
                     int total4, float invN, int relu)
{
    int idx = blockIdx.x * blockDim.x + threadIdx.x;
    if (idx < total4) {
        int c4 = idx & 31;
        float4 x  = ((const float4*)hl)[idx];
        float4 s1 = ((const float4*)stats)[c4];
        float4 s2 = ((const float4*)stats)[32 + c4];
        float4 g  = ((const float4*)gam)[c4];
        float4 b  = ((const float4*)bet)[c4];
        float4 r;
        {
            float m = s1.x * invN; float v = s2.x * invN - m * m;
            r.x = fmaf((x.x - m) * rsqrtf(v + LN_EPS), g.x, b.x);
        }
        {
            float m = s1.y * invN; float v = s2.y * invN - m * m;
            r.y = fmaf((x.y - m) * rsqrtf(v + LN_EPS), g.y, b.y);
        }
        {
            float m = s1.z * invN; float v = s2.z * invN - m * m;
            r.z = fmaf((x.z - m) * rsqrtf(v + LN_EPS), g.z, b.z);
        }
        {
            float m = s1.w * invN; float v = s2.w * invN - m * m;
            r.w = fmaf((x.w - m) * rsqrtf(v + LN_EPS), g.w, b.w);
        }
        if (relu) {
            r.x = fmaxf(r.x, 0.f); r.y = fmaxf(r.y, 0.f);
            r.z = fmaxf(r.z, 0.f); r.w = fmaxf(r.w, 0.f);
        }
        if (out16) {
            half4v o;
            o.x = (_Float16)r.x; o.y = (_Float16)r.y;
            o.z = (_Float16)r.z; o.w = (_Float16)r.w;
            *(half4v*)&out16[(size_t)idx * 4] = o;
        } else {
            ((float4*)out32)[idx] = r;
        }
    }
}

extern "C" void kernel_launch(void* const* d_in, const int* in_sizes, int n_in,
                              void* d_out, int out_size, void* d_ws, size_t ws_size,
                              hipStream_t stream)
{
    const float* x       = (const float*)d_in[0];
    const int*   ei      = (const int*)d_in[1];
    const float* eattr   = (const float*)d_in[2];
    const float* node_W  = (const float*)d_in[3];
    const float* node_b  = (const float*)d_in[4];
    const float* node_g  = (const float*)d_in[5];
    const float* node_be = (const float*)d_in[6];
    const float* edge_W  = (const float*)d_in[7];
    const float* edge_b  = (const float*)d_in[8];
    const float* edge_g  = (const float*)d_in[9];
    const float* edge_be = (const float*)d_in[10];
    const float* sl_attr = (const float*)d_in[11];
    const float* W1      = (const float*)d_in[12];
    const float* b1      = (const float*)d_in[13];
    const float* W2      = (const float*)d_in[14];
    const float* b2      = (const float*)d_in[15];
    const float* bn_g    = (const float*)d_in[16];
    const float* bn_b    = (const float*)d_in[17];

    const int N = in_sizes[0] / NODED;
    const int E = in_sizes[1] / 2;

    // explicit 16B-aligned workspace layout
    char* base = (char*)d_ws;
    size_t off = 0;
    auto take = [&](size_t nbytes) -> void* {
        void* p = base + off;
        off = (off + nbytes + 15) & ~(size_t)15;
        return p;
    };
    _Float16* h16  = (_Float16*)take((size_t)N * HD * 2); // node features (fp16)
    float*  z      = (float*)take((size_t)N * HD * 4);     // node-embed pre-LN (fp32)
    __bf16* aghi   = (__bf16*)take((size_t)N * HD * 2);    // aggr bf16 hi
    __bf16* aglo   = (__bf16*)take((size_t)N * HD * 2);
    _Float16* z16  = (_Float16*)take((size_t)N * 256 * 2); // mlp1 out fp16
    __bf16* xhi    = (__bf16*)take((size_t)N * NODED * 2);
    __bf16* xlo    = (__bf16*)take((size_t)N * NODED * 2);
    float*  slv3   = (float*)take(3 * HD * 4);
    float*  stats  = (float*)take(3 * 256 * 4);
    int*    cnt    = (int*)take((size_t)N * 4);
    int*    cursor = (int*)take((size_t)N * 4);
    int*    bsum   = (int*)take(256 * 4);
    int*    boff   = (int*)take(256 * 4);
    int*    rs     = (int*)take(((size_t)N + 2) * 4);
    int2*   es     = (int2*)take((size_t)E * 8);
    unsigned* sei  = (unsigned*)take((size_t)3 * E * 4);   // packed (src16, iv-fp16)
    _Float16* attr16 = (_Float16*)take((size_t)E * EDGED * 2); // slot-permuted fp16 attrs
    _Float16* Wg16_3 = (_Float16*)take(3 * 2048 * 2);      // fp16 edge weights [c][k]
    float*  bg3    = (float*)take(3 * HD * 4);
    float*  M3     = (float*)take(3 * 256 * 4);
    float*  v3     = (float*)take(3 * 16 * 4);
    float*  s03    = (float*)take(4 * 4);
    __bf16* nWhi   = (__bf16*)take((size_t)HD * NODED * 2);
    __bf16* nWlo   = (__bf16*)take((size_t)HD * NODED * 2);
    __bf16* W1hi   = (__bf16*)take((size_t)3 * 256 * HD * 2);
    __bf16* W1lo   = (__bf16*)take((size_t)3 * 256 * HD * 2);
    _Float16* W2h16 = (_Float16*)take((size_t)3 * HD * 256 * 2);
    _Float16* W2l16 = (_Float16*)take((size_t)3 * HD * 256 * 2);

    // weight splits: node/W1 bf16 hi/lo, W2 fp16 hi/lo, x bf16 hi/lo
    wconv_k<<<(HD * NODED + 255) / 256, 256, 0, stream>>>(node_W, nWhi, nWlo, HD * NODED);
    wconv_k<<<(3 * 256 * HD + 255) / 256, 256, 0, stream>>>(W1, W1hi, W1lo, 3 * 256 * HD);
    wconv16_k<<<(3 * 256 * HD + 255) / 256, 256, 0, stream>>>(W2, W2h16, W2l16, 3 * 256 * HD);
    wconv_k<<<((int)((size_t)N * NODED + 255) / 256), 256, 0, stream>>>(x, xhi, xlo, N * NODED);

    // edge-LN precompute + self-loop embed + fp16 weights (all 3 layers)
    prep_k<<<3, 256, 0, stream>>>(edge_W, edge_b, edge_g, edge_be, sl_attr,
                                  Wg16_3, bg3, M3, v3, s03, slv3);

    // ---- CSR build ----
    const int eblocks = (E + 255) / 256;
    const int nblocks = (N + 255) / 256;
    hipMemsetAsync(cnt, 0, (size_t)N * sizeof(int), stream);
    hist_k<<<eblocks, 256, 0, stream>>>(ei, cnt, E);
    scan1_k<<<nblocks, 256, 0, stream>>>(cnt, rs, bsum, N);
    scan2_k<<<1, 256, 0, stream>>>(bsum, boff, nblocks);
    scan3_k<<<nblocks, 256, 0, stream>>>(rs, cursor, boff, N, E);
    scatter_k<<<eblocks, 256, 0, stream>>>(ei, cursor, es, E);

    // per-slot packed (src, iv) for all 3 layers + permuted fp16 attr stream
    einv_k<<<eblocks, 256, 0, stream>>>(es, eattr, M3, v3, s03, sei, attr16, E);

    const int total4  = N * (HD / 4);
    const int vblocks = (total4 + 255) / 256;
    const int gb128   = (N + 127) / 128;
    int pgrid = (N + 3) / 4;
    if (pgrid > 2048) pgrid = 2048;           // persistent: 8192 waves

    // node embed: Linear (MFMA) -> LN -> ReLU
    mgemm_k<NODED, HD, 0, 0, 0, 0><<<dim3(gb128, 2), 256, 0, stream>>>(
        xhi, xlo, nWhi, nWlo, node_b, z, nullptr, N, nullptr);
    ln_relu_k<<<(N + 3) / 4, 256, 0, stream>>>(z, node_g, node_be, h16, N);

    hipMemsetAsync(stats, 0, 3 * 256 * sizeof(float), stream);

    for (int l = 0; l < 3; ++l) {
        pull9_k<<<pgrid, 256, 0, stream>>>(h16, rs, attr16, sei + (size_t)l * E,
                                           slv3 + l * HD, Wg16_3 + (size_t)l * 2048,
                                           bg3 + l * HD, edge_be + l * HD,
                                           aghi, aglo, N);

        // mlp1: bf16 hi/lo A x bf16 hi/lo W -> gelu -> fp16 z
        mgemm_k<HD, 256, 1, 0, 0, 2><<<dim3(gb128, 4), 256, 0, stream>>>(
            aghi, aglo, W1hi + (size_t)l * 256 * HD, W1lo + (size_t)l * 256 * HD,
            b1 + l * 256, nullptr, z16, N, nullptr);

        // mlp2: fp16 A x fp16 hi/lo W -> fp32 + stats
        mgemm_k<256, HD, 0, 1, 1, 0><<<dim3(gb128, 2), 256, 0, stream>>>(
            z16, nullptr, W2h16 + (size_t)l * HD * 256, W2l16 + (size_t)l * HD * 256,
            b2 + l * HD, (float*)d_out, nullptr, N, stats + l * 256);

        bn_k<<<vblocks, 256, 0, stream>>>((const float*)d_out, stats + l * 256,
                                          bn_g + l * HD, bn_b + l * HD,
                                          (float*)d_out, (l < 2) ? h16 : nullptr,
                                          total4, 1.f / N, (l < 2) ? 1 : 0);
    }
}

// Round 8
// 871.673 us; speedup vs baseline: 1.4742x; 1.0003x over previous
//
#include <hip/hip_runtime.h>
#include <cstdint>
#include <cstddef>

#define HD 128
#define EDGED 16
#define NODED 64
#define LN_EPS 1e-5f

typedef __bf16 bf16x8 __attribute__((ext_vector_type(8)));
typedef float  f32x4  __attribute__((ext_vector_type(4)));
typedef _Float16 half2v __attribute__((ext_vector_type(2)));
typedef _Float16 half4v __attribute__((ext_vector_type(4)));
typedef _Float16 half8v __attribute__((ext_vector_type(8)));

union HU { half8v v; half2v p[4]; };

__device__ __forceinline__ float gelu_exact(float x) {
    return 0.5f * x * (1.0f + erff(x * 0.7071067811865475f));
}

__device__ __forceinline__ float hi16_to_f(int bits) {
    union { unsigned short u; _Float16 h; } c;
    c.u = (unsigned short)((unsigned)bits >> 16);
    return (float)c.h;
}

// fp32 -> bf16 hi/lo split (a ~= hi + lo, lo captures the rounding residual)
__global__ void wconv_k(const float* __restrict__ in, __bf16* __restrict__ hi,
                        __bf16* __restrict__ lo, int n) {
    int i = blockIdx.x * blockDim.x + threadIdx.x;
    if (i < n) {
        float v = in[i];
        __bf16 h = (__bf16)v;
        hi[i] = h;
        lo[i] = (__bf16)(v - (float)h);
    }
}

// fp32 -> fp16 hi/lo split
__global__ void wconv16_k(const float* __restrict__ in, _Float16* __restrict__ hi,
                          _Float16* __restrict__ lo, int n) {
    int i = blockIdx.x * blockDim.x + threadIdx.x;
    if (i < n) {
        float v = in[i];
        _Float16 h = (_Float16)v;
        hi[i] = h;
        lo[i] = (_Float16)(v - (float)h);
    }
}

// ---------------- CSR build ----------------

__global__ void hist_k(const int* __restrict__ ei, int* __restrict__ cnt, int E) {
    int e = blockIdx.x * blockDim.x + threadIdx.x;
    if (e < E) atomicAdd(&cnt[ei[E + e]], 1);
}

__global__ void scan1_k(const int* __restrict__ in, int* __restrict__ out,
                        int* __restrict__ bsum, int n) {
    __shared__ int lds[256];
    int t = threadIdx.x;
    int i = blockIdx.x * 256 + t;
    int v = (i < n) ? in[i] : 0;
    lds[t] = v;
    __syncthreads();
#pragma unroll
    for (int o = 1; o < 256; o <<= 1) {
        int u = (t >= o) ? lds[t - o] : 0;
        __syncthreads();
        lds[t] += u;
        __syncthreads();
    }
    if (i < n) out[i] = lds[t] - v;
    if (t == 255) bsum[blockIdx.x] = lds[255];
}

__global__ void scan2_k(const int* __restrict__ bsum, int* __restrict__ boff, int nb) {
    __shared__ int lds[256];
    int t = threadIdx.x;
    int v = (t < nb) ? bsum[t] : 0;
    lds[t] = v;
    __syncthreads();
#pragma unroll
    for (int o = 1; o < 256; o <<= 1) {
        int u = (t >= o) ? lds[t - o] : 0;
        __syncthreads();
        lds[t] += u;
        __syncthreads();
    }
    if (t < nb) boff[t] = lds[t] - v;
}

// adds block offsets; also emits the scatter cursor copy (saves a d2d memcpy)
__global__ void scan3_k(int* __restrict__ rs, int* __restrict__ cursor,
                        const int* __restrict__ boff, int n, int E) {
    int i = blockIdx.x * 256 + threadIdx.x;
    if (i < n) {
        int v = rs[i] + boff[blockIdx.x];
        rs[i] = v;
        cursor[i] = v;
    }
    if (i == 0) rs[n] = E;
}

__global__ void scatter_k(const int* __restrict__ ei, int* __restrict__ cursor,
                          int2* __restrict__ es, int E) {
    int e = blockIdx.x * blockDim.x + threadIdx.x;
    if (e < E) {
        int dst = ei[E + e];
        int slot = atomicAdd(&cursor[dst], 1);
        es[slot] = make_int2(ei[e], e);
    }
}

// ---------------- edge-LN precompute (+ fused self-loop embed) ----------------
__global__ void prep_k(const float* __restrict__ edge_W, const float* __restrict__ edge_b,
                       const float* __restrict__ edge_g, const float* __restrict__ edge_be,
                       const float* __restrict__ sl_attr, _Float16* __restrict__ Wg16_3,
                       float* __restrict__ bg3, float* __restrict__ M3,
                       float* __restrict__ v3, float* __restrict__ s03,
                       float* __restrict__ slv3)
{
    const int l = blockIdx.x;
    const float* W = edge_W + (size_t)l * HD * EDGED;
    const float* b = edge_b + l * HD;
    const float* g = edge_g + l * HD;
    __shared__ float Wp[HD * EDGED];
    __shared__ float bp[HD];
    __shared__ float wm[EDGED];
    __shared__ float Msh[256];
    __shared__ float vsh[EDGED];
    __shared__ float ash[EDGED];
    __shared__ float bmS, s0sh;
    const int t = threadIdx.x;
#pragma unroll
    for (int m = 0; m < 8; ++m) Wp[m * 256 + t] = W[m * 256 + t];
    __syncthreads();
    if (t < EDGED) {
        float s = 0.f;
        for (int c = 0; c < HD; ++c) s += Wp[c * EDGED + t];
        wm[t] = s * (1.f / HD);
    } else if (t == EDGED) {
        float s = 0.f;
        for (int c = 0; c < HD; ++c) s += b[c];
        bmS = s * (1.f / HD);
    }
    __syncthreads();
    if (t < HD) bp[t] = b[t] - bmS;
    __syncthreads();
#pragma unroll
    for (int m = 0; m < 8; ++m) {
        int idx = m * 256 + t;
        int c = idx >> 4, k = idx & 15;
        float val = Wp[idx] - wm[k];
        Wp[idx] = val;
        Wg16_3[(size_t)l * 2048 + idx] = (_Float16)(val * g[c]);   // [c][k] layout
    }
    if (t < HD) bg3[l * HD + t] = bp[t] * g[t];
    __syncthreads();
    {
        int k = t >> 4, j = t & 15;
        float s = 0.f;
        for (int c = 0; c < HD; ++c) s += Wp[c * EDGED + k] * Wp[c * EDGED + j];
        Msh[t] = s;
        M3[l * 256 + t] = s;
    }
    if (t < EDGED) {
        float s = 0.f;
        for (int c = 0; c < HD; ++c) s += Wp[c * EDGED + t] * bp[c];
        vsh[t] = 2.f * s;
        v3[l * EDGED + t] = 2.f * s;
        ash[t] = sl_attr[l * EDGED + t];
    } else if (t == EDGED) {
        float s = 0.f;
        for (int c = 0; c < HD; ++c) s += bp[c] * bp[c];
        s0sh = s;
        s03[l] = s;
    }
    __syncthreads();
    // self-loop embed: out_c = ((Wp.a)*g + bg)*inv + bet, relu
    if (t < HD) {
        float q = s0sh;
#pragma unroll
        for (int k = 0; k < EDGED; ++k) {
            float tk = vsh[k];
#pragma unroll
            for (int j = 0; j < EDGED; ++j) tk = fmaf(Msh[k * 16 + j], ash[j], tk);
            q = fmaf(ash[k], tk, q);
        }
        float inv = rsqrtf(q * (1.f / HD) + LN_EPS);
        float y = 0.f;
#pragma unroll
        for (int k = 0; k < EDGED; ++k) y = fmaf(Wp[t * EDGED + k], ash[k], y);
        slv3[l * HD + t] = fmaxf(fmaf(fmaf(y, g[t], bg3[l * HD + t]), inv, edge_be[l * HD + t]), 0.f);
    }
}

// Per CSR slot: gather attr row once; emit PACKED meta per layer:
// low 16 bits = src node id (N < 65536), high 16 bits = fp16 inv-std.
// Also emits the attr row PERMUTED into slot order as fp16 (attr16).
__launch_bounds__(256)
__global__ void einv_k(const int2* __restrict__ es, const float* __restrict__ eattr,
                       const float* __restrict__ M3, const float* __restrict__ v3,
                       const float* __restrict__ s03, unsigned* __restrict__ sei,
                       _Float16* __restrict__ attr16, int E)
{
    __shared__ float Ms[3 * 256];
    __shared__ float vs[3 * 16];
    __shared__ float s0s[4];
    const int t = threadIdx.x;
    for (int i = t; i < 768; i += 256) Ms[i] = M3[i];
    if (t < 48) vs[t] = v3[t];
    if (t < 3) s0s[t] = s03[t];
    __syncthreads();
    int slot = blockIdx.x * 256 + t;
    if (slot >= E) return;
    int2 se = es[slot];
    const float4* ap = (const float4*)(eattr + (size_t)se.y * EDGED);
    float4 A0 = ap[0], A1 = ap[1], A2 = ap[2], A3 = ap[3];
    float a[16] = {A0.x, A0.y, A0.z, A0.w, A1.x, A1.y, A1.z, A1.w,
                   A2.x, A2.y, A2.z, A2.w, A3.x, A3.y, A3.z, A3.w};
    {
        half8v o0, o1;
#pragma unroll
        for (int i = 0; i < 8; ++i) { o0[i] = (_Float16)a[i]; o1[i] = (_Float16)a[8 + i]; }
        _Float16* op = attr16 + (size_t)slot * EDGED;
        *(half8v*)&op[0] = o0;
        *(half8v*)&op[8] = o1;
    }
#pragma unroll
    for (int l = 0; l < 3; ++l) {
        float q = s0s[l];
#pragma unroll
        for (int k = 0; k < 16; ++k) {
            const float* Mr = &Ms[l * 256 + k * 16];
            float tk = vs[l * 16 + k];
#pragma unroll
            for (int j = 0; j < 16; ++j) tk = fmaf(Mr[j], a[j], tk);
            q = fmaf(a[k], tk, q);
        }
        float iv = rsqrtf(q * (1.f / HD) + LN_EPS);
        union { _Float16 h; unsigned short u; } cv;
        cv.h = (_Float16)iv;
        sei[(size_t)l * E + slot] = ((unsigned)se.x & 0xFFFFu) | ((unsigned)cv.u << 16);
    }
}

// ---------------- MFMA GEMM v3 ---------------------------------------------
// AMODE 0: A bf16 hi/lo + W bf16 hi/lo (3 MFMA, ~fp32 accuracy)
// AMODE 1: A fp16 single + W fp16 hi/lo (2 MFMA f16)
// OUTMODE 0: fp32 C; 2: fp16 single (Co1)
template<int K, int NC, int ACT, int STATS, int AMODE, int OUTMODE>
__launch_bounds__(256)
__global__ void mgemm_k(const void* __restrict__ Ap1, const void* __restrict__ Ap2,
                        const void* __restrict__ Wp1, const void* __restrict__ Wp2,
                        const float* __restrict__ bias, float* __restrict__ C,
                        void* __restrict__ Co1, int M, float* __restrict__ stats)
{
    constexpr int RG = 2;
    constexpr int NT = 4;
    constexpr int NK = K / 32;
    __shared__ float st_lds[2][64];

    const int t    = threadIdx.x;
    const int lane = t & 63;
    const int wv   = t >> 6;
    const int ln15 = lane & 15;
    const int quad = lane >> 4;
    const int row_base = blockIdx.x * 128 + wv * 32;
    const int col0 = blockIdx.y * 64;

    f32x4 acc[RG][NT];
#pragma unroll
    for (int g = 0; g < RG; ++g)
#pragma unroll
        for (int nt = 0; nt < NT; ++nt)
#pragma unroll
            for (int r = 0; r < 4; ++r) acc[g][nt][r] = 0.f;

    size_t arow[RG];
#pragma unroll
    for (int g = 0; g < RG; ++g) {
        int row = row_base + g * 16 + ln15;
        row = row < M ? row : M - 1;          // clamp: junk values, store masked
        arow[g] = (size_t)row * K + quad * 8;
    }
    size_t brow[NT];
#pragma unroll
    for (int nt = 0; nt < NT; ++nt)
        brow[nt] = (size_t)(col0 + nt * 16 + ln15) * K + quad * 8;

    if constexpr (AMODE == 0) {
        const __bf16* Ahi = (const __bf16*)Ap1;
        const __bf16* Alo = (const __bf16*)Ap2;
        const __bf16* Whi = (const __bf16*)Wp1;
        const __bf16* Wlo = (const __bf16*)Wp2;
        bf16x8 a0h[RG], a0l[RG], a1h[RG], a1l[RG];
        bf16x8 b0h[NT], b0l[NT], b1h[NT], b1l[NT];

#define LD_A(kc, AH, AL) { \
    _Pragma("unroll") \
    for (int g = 0; g < RG; ++g) { \
        AH[g] = *(const bf16x8*)(Ahi + arow[g] + (kc)); \
        AL[g] = *(const bf16x8*)(Alo + arow[g] + (kc)); \
    } }
#define LD_B(kc, BH, BL) { \
    _Pragma("unroll") \
    for (int nt = 0; nt < NT; ++nt) { \
        BH[nt] = *(const bf16x8*)(Whi + brow[nt] + (kc)); \
        BL[nt] = *(const bf16x8*)(Wlo + brow[nt] + (kc)); \
    } }
#define DO_MFMA(AH, AL, BH, BL) { \
    _Pragma("unroll") \
    for (int nt = 0; nt < NT; ++nt) { \
        _Pragma("unroll") \
        for (int g = 0; g < RG; ++g) { \
            acc[g][nt] = __builtin_amdgcn_mfma_f32_16x16x32_bf16(AH[g], BH[nt], acc[g][nt], 0, 0, 0); \
            acc[g][nt] = __builtin_amdgcn_mfma_f32_16x16x32_bf16(AH[g], BL[nt], acc[g][nt], 0, 0, 0); \
            acc[g][nt] = __builtin_amdgcn_mfma_f32_16x16x32_bf16(AL[g], BH[nt], acc[g][nt], 0, 0, 0); \
        } } }

        LD_A(0, a0h, a0l);
        LD_B(0, b0h, b0l);
        for (int s = 0; s < NK; s += 2) {
            LD_A((s + 1) * 32, a1h, a1l);
            LD_B((s + 1) * 32, b1h, b1l);
            DO_MFMA(a0h, a0l, b0h, b0l);
            if (s + 2 < NK) {
                LD_A((s + 2) * 32, a0h, a0l);
                LD_B((s + 2) * 32, b0h, b0l);
            }
            DO_MFMA(a1h, a1l, b1h, b1l);
        }
#undef LD_A
#undef LD_B
#undef DO_MFMA
    } else {
        const _Float16* Af = (const _Float16*)Ap1;
        const _Float16* Wh = (const _Float16*)Wp1;
        const _Float16* Wl = (const _Float16*)Wp2;
        half8v a0[RG], a1[RG];
        half8v b0h[NT], b0l[NT], b1h[NT], b1l[NT];

#define LD_A16(kc, A) { \
    _Pragma("unroll") \
    for (int g = 0; g < RG; ++g) A[g] = *(const half8v*)(Af + arow[g] + (kc)); }
#define LD_B16(kc, BH, BL) { \
    _Pragma("unroll") \
    for (int nt = 0; nt < NT; ++nt) { \
        BH[nt] = *(const half8v*)(Wh + brow[nt] + (kc)); \
        BL[nt] = *(const half8v*)(Wl + brow[nt] + (kc)); \
    } }
#define DO_MFMA16(A, BH, BL) { \
    _Pragma("unroll") \
    for (int nt = 0; nt < NT; ++nt) { \
        _Pragma("unroll") \
        for (int g = 0; g < RG; ++g) { \
            acc[g][nt] = __builtin_amdgcn_mfma_f32_16x16x32_f16(A[g], BH[nt], acc[g][nt], 0, 0, 0); \
            acc[g][nt] = __builtin_amdgcn_mfma_f32_16x16x32_f16(A[g], BL[nt], acc[g][nt], 0, 0, 0); \
        } } }

        LD_A16(0, a0);
        LD_B16(0, b0h, b0l);
        for (int s = 0; s < NK; s += 2) {
            LD_A16((s + 1) * 32, a1);
            LD_B16((s + 1) * 32, b1h, b1l);
            DO_MFMA16(a0, b0h, b0l);
            if (s + 2 < NK) {
                LD_A16((s + 2) * 32, a0);
                LD_B16((s + 2) * 32, b0h, b0l);
            }
            DO_MFMA16(a1, b1h, b1l);
        }
#undef LD_A16
#undef LD_B16
#undef DO_MFMA16
    }

    if (STATS) {
        if (t < 64) { st_lds[0][t] = 0.f; st_lds[1][t] = 0.f; }
        __syncthreads();
    }

    float bv[NT];
#pragma unroll
    for (int nt = 0; nt < NT; ++nt) bv[nt] = bias[col0 + nt * 16 + ln15];

    float s1[NT], s2[NT];
#pragma unroll
    for (int nt = 0; nt < NT; ++nt) { s1[nt] = 0.f; s2[nt] = 0.f; }

#pragma unroll
    for (int g = 0; g < RG; ++g)
#pragma unroll
        for (int r = 0; r < 4; ++r) {
            int row = row_base + g * 16 + quad * 4 + r;
            if (row < M) {
#pragma unroll
                for (int nt = 0; nt < NT; ++nt) {
                    float v = acc[g][nt][r] + bv[nt];
                    if (ACT == 1) v = gelu_exact(v);
                    size_t ci = (size_t)row * NC + col0 + nt * 16 + ln15;
                    if (OUTMODE == 2) {
                        ((_Float16*)Co1)[ci] = (_Float16)v;
                    } else {
                        C[ci] = v;
                    }
                    if (STATS) { s1[nt] += v; s2[nt] += v * v; }
                }
            }
        }

    if (STATS) {
#pragma unroll
        for (int nt = 0; nt < NT; ++nt) {
            atomicAdd(&st_lds[0][nt * 16 + ln15], s1[nt]);
            atomicAdd(&st_lds[1][nt * 16 + ln15], s2[nt]);
        }
        __syncthreads();
        if (t < 64) {
            atomicAdd(&stats[col0 + t],      st_lds[0][t]);
            atomicAdd(&stats[HD + col0 + t], st_lds[1][t]);
        }
    }
}

// ---------------- fused node-embed: GEMM(K=64) + LayerNorm + ReLU -> fp16 --
// One block = 128 rows x ALL 128 cols (NT=8). LN reduce: per output row the
// 128 values live in the 16 lanes of one quad-group (8 per lane) -> 8 local
// adds + shfl_xor(1,2,4,8). Eliminates the fp32 z buffer + ln_relu pass.
__launch_bounds__(256)
__global__ void nemb_k(const __bf16* __restrict__ Ahi, const __bf16* __restrict__ Alo,
                       const __bf16* __restrict__ Whi, const __bf16* __restrict__ Wlo,
                       const float* __restrict__ bias, const float* __restrict__ gam,
                       const float* __restrict__ bet, _Float16* __restrict__ h16, int M)
{
    constexpr int RG = 2;
    constexpr int NT = 8;
    const int t    = threadIdx.x;
    const int lane = t & 63;
    const int wv   = t >> 6;
    const int ln15 = lane & 15;
    const int quad = lane >> 4;
    const int row_base = blockIdx.x * 128 + wv * 32;

    f32x4 acc[RG][NT];
#pragma unroll
    for (int g = 0; g < RG; ++g)
#pragma unroll
        for (int nt = 0; nt < NT; ++nt)
#pragma unroll
            for (int r = 0; r < 4; ++r) acc[g][nt][r] = 0.f;

    size_t arow[RG];
#pragma unroll
    for (int g = 0; g < RG; ++g) {
        int row = row_base + g * 16 + ln15;
        row = row < M ? row : M - 1;
        arow[g] = (size_t)row * NODED + quad * 8;
    }
    size_t brow[NT];
#pragma unroll
    for (int nt = 0; nt < NT; ++nt)
        brow[nt] = (size_t)(nt * 16 + ln15) * NODED + quad * 8;

#pragma unroll
    for (int s = 0; s < 2; ++s) {
        bf16x8 ah[RG], al[RG];
#pragma unroll
        for (int g = 0; g < RG; ++g) {
            ah[g] = *(const bf16x8*)(Ahi + arow[g] + s * 32);
            al[g] = *(const bf16x8*)(Alo + arow[g] + s * 32);
        }
#pragma unroll
        for (int nt = 0; nt < NT; ++nt) {
            bf16x8 bh = *(const bf16x8*)(Whi + brow[nt] + s * 32);
            bf16x8 bl = *(const bf16x8*)(Wlo + brow[nt] + s * 32);
#pragma unroll
            for (int g = 0; g < RG; ++g) {
                acc[g][nt] = __builtin_amdgcn_mfma_f32_16x16x32_bf16(ah[g], bh, acc[g][nt], 0, 0, 0);
                acc[g][nt] = __builtin_amdgcn_mfma_f32_16x16x32_bf16(ah[g], bl, acc[g][nt], 0, 0, 0);
                acc[g][nt] = __builtin_amdgcn_mfma_f32_16x16x32_bf16(al[g], bh, acc[g][nt], 0, 0, 0);
            }
        }
    }

    float bv[NT], gv[NT], betv[NT];
#pragma unroll
    for (int nt = 0; nt < NT; ++nt) {
        int col = nt * 16 + ln15;
        bv[nt]   = bias[col];
        gv[nt]   = gam[col];
        betv[nt] = bet[col];
    }

#pragma unroll
    for (int g = 0; g < RG; ++g)
#pragma unroll
        for (int r = 0; r < 4; ++r) {
            int row = row_base + g * 16 + quad * 4 + r;
            float v[NT];
            float s = 0.f, q = 0.f;
#pragma unroll
            for (int nt = 0; nt < NT; ++nt) {
                v[nt] = acc[g][nt][r] + bv[nt];
                s += v[nt];
                q += v[nt] * v[nt];
            }
#pragma unroll
            for (int o = 8; o > 0; o >>= 1) {
                s += __shfl_xor(s, o, 64);
                q += __shfl_xor(q, o, 64);
            }
            float mu  = s * (1.f / 128.f);
            float inv = rsqrtf(q * (1.f / 128.f) - mu * mu + LN_EPS);
            if (row < M) {
#pragma unroll
                for (int nt = 0; nt < NT; ++nt) {
                    float rr = fmaxf(fmaf((v[nt] - mu) * inv, gv[nt], betv[nt]), 0.f);
                    h16[(size_t)row * HD + nt * 16 + ln15] = (_Float16)rr;
                }
            }
        }
}

// ---------------- pull aggregation v9: packed meta + fdot2 -----------------
__launch_bounds__(256)
__global__ void pull9_k(const _Float16* __restrict__ h16, const int* __restrict__ rs,
                        const _Float16* __restrict__ attr16, const unsigned* __restrict__ sei,
                        const float* __restrict__ slv, const _Float16* __restrict__ Wg16,
                        const float* __restrict__ bg, const float* __restrict__ bet,
                        __bf16* __restrict__ Ahi, __bf16* __restrict__ Alo, int N)
{
    __shared__ _Float16 alds_all[4][64 * EDGED];   // 8 KB: per-wave attr staging
    const int t = threadIdx.x;
    const int lane = t & 63;
    const int wv = t >> 6;
    _Float16* alds = alds_all[wv];
    uint4* alds4 = (uint4*)alds;

    const int c0 = lane * 2;
    half2v w0p[8], w1p[8];
#pragma unroll
    for (int k = 0; k < 8; ++k) {
        w0p[k] = *(const half2v*)&Wg16[c0 * EDGED + 2 * k];
        w1p[k] = *(const half2v*)&Wg16[(c0 + 1) * EDGED + 2 * k];
    }
    const float2 bgv  = *(const float2*)&bg[c0];
    const float2 btv  = *(const float2*)&bet[c0];
    const float2 slvv = *(const float2*)&slv[c0];

    const int stride = gridDim.x << 2;
    for (int n = (blockIdx.x << 2) + wv; n < N; n += stride) {
        half2v hs = *(const half2v*)&h16[(size_t)n * HD + c0];
        float acc0 = (float)hs.x + slvv.x;
        float acc1 = (float)hs.y + slvv.y;

        const int beg = rs[n], end = rs[n + 1];
        for (int s0 = beg; s0 < end; s0 += 64) {
            int m = end - s0; if (m > 64) m = 64;
            int sv = 0;
            if (lane < m) sv = (int)sei[s0 + lane];
            // stage fp16 attrs: contiguous stream copy, 32B/edge
            const uint4* src4 = (const uint4*)(attr16 + (size_t)s0 * EDGED);
#pragma unroll
            for (int it = 0; it < 2; ++it) {
                int idx = (it << 6) + lane;
                if (idx < (m << 1)) alds4[idx] = src4[idx];
            }
            asm volatile("s_waitcnt lgkmcnt(0)" ::: "memory");

#define EDGE_BODY(JJ, IVJ, HVJ) { \
            HU ua, ub; \
            ua.v = *(const half8v*)&alds[(JJ) * EDGED]; \
            ub.v = *(const half8v*)&alds[(JJ) * EDGED + 8]; \
            float p0 = bgv.x, q0 = 0.f, p1 = bgv.y, q1 = 0.f; \
            p0 = __builtin_amdgcn_fdot2(ua.p[0], w0p[0], p0, false); \
            q0 = __builtin_amdgcn_fdot2(ua.p[1], w0p[1], q0, false); \
            p1 = __builtin_amdgcn_fdot2(ua.p[0], w1p[0], p1, false); \
            q1 = __builtin_amdgcn_fdot2(ua.p[1], w1p[1], q1, false); \
            p0 = __builtin_amdgcn_fdot2(ua.p[2], w0p[2], p0, false); \
            q0 = __builtin_amdgcn_fdot2(ua.p[3], w0p[3], q0, false); \
            p1 = __builtin_amdgcn_fdot2(ua.p[2], w1p[2], p1, false); \
            q1 = __builtin_amdgcn_fdot2(ua.p[3], w1p[3], q1, false); \
            p0 = __builtin_amdgcn_fdot2(ub.p[0], w0p[4], p0, false); \
            q0 = __builtin_amdgcn_fdot2(ub.p[1], w0p[5], q0, false); \
            p1 = __builtin_amdgcn_fdot2(ub.p[0], w1p[4], p1, false); \
            q1 = __builtin_amdgcn_fdot2(ub.p[1], w1p[5], q1, false); \
            p0 = __builtin_amdgcn_fdot2(ub.p[2], w0p[6], p0, false); \
            q0 = __builtin_amdgcn_fdot2(ub.p[3], w0p[7], q0, false); \
            p1 = __builtin_amdgcn_fdot2(ub.p[2], w1p[6], p1, false); \
            q1 = __builtin_amdgcn_fdot2(ub.p[3], w1p[7], q1, false); \
            acc0 += fmaxf(fmaf(p0 + q0, IVJ, btv.x), 0.f) + (float)HVJ.x; \
            acc1 += fmaxf(fmaf(p1 + q1, IVJ, btv.y), 0.f) + (float)HVJ.y; \
        }

            int j = 0;
            for (; j + 4 <= m; j += 4) {
                int v0 = __shfl(sv, j,     64);
                int v1 = __shfl(sv, j + 1, 64);
                int v2 = __shfl(sv, j + 2, 64);
                int v3 = __shfl(sv, j + 3, 64);
                int s_0 = v0 & 0xFFFF, s_1 = v1 & 0xFFFF;
                int s_2 = v2 & 0xFFFF, s_3 = v3 & 0xFFFF;
                float i0 = hi16_to_f(v0);
                float i1 = hi16_to_f(v1);
                float i2 = hi16_to_f(v2);
                float i3 = hi16_to_f(v3);
                half2v h0 = *(const half2v*)&h16[(size_t)s_0 * HD + c0];
                half2v h1 = *(const half2v*)&h16[(size_t)s_1 * HD + c0];
                half2v h2 = *(const half2v*)&h16[(size_t)s_2 * HD + c0];
                half2v h3 = *(const half2v*)&h16[(size_t)s_3 * HD + c0];
                EDGE_BODY(j,     i0, h0);
                EDGE_BODY(j + 1, i1, h1);
                EDGE_BODY(j + 2, i2, h2);
                EDGE_BODY(j + 3, i3, h3);
            }
            for (; j < m; ++j) {
                int vj = __shfl(sv, j, 64);
                int s_ = vj & 0xFFFF;
                float ij = hi16_to_f(vj);
                half2v hj = *(const half2v*)&h16[(size_t)s_ * HD + c0];
                EDGE_BODY(j, ij, hj);
            }
#undef EDGE_BODY
        }
        __bf16 b0 = (__bf16)acc0, b1 = (__bf16)acc1;
        union { __bf16 b[2]; unsigned u; } ph, pl;
        ph.b[0] = b0;
        ph.b[1] = b1;
        pl.b[0] = (__bf16)(acc0 - (float)b0);
        pl.b[1] = (__bf16)(acc1 - (float)b1);
        *(unsigned*)&Ahi[(size_t)n * HD + c0] = ph.u;
        *(unsigned*)&Alo[(size_t)n * HD + c0] = pl.u;
    }
}

// BatchNorm apply from accumulated column sums; input fp16, optional ReLU.
// out16 != null -> write fp16 (h for next layer); else fp32 to out32.
__global__ void bn_k(const _Float16* __restrict__ hl, const float* __restrict__ stats,
                     const float* __restrict__ gam, const float* __restrict__ bet,
                     float* __restrict__ out32, _Float16* __restrict__ out16,
                     int total4, float invN, int relu)
{
    int idx = blockIdx.x * blockDim.x + threadIdx.x;
    if (idx < total4) {
        int c4 = idx & 31;
        half4v xh = *(const half4v*)&hl[(size_t)idx * 4];
        float4 s1 = ((const float4*)stats)[c4];
        float4 s2 = ((const float4*)stats)[32 + c4];
        float4 g  = ((const float4*)gam)[c4];
        float4 b  = ((const float4*)bet)[c4];
        float4 r;
        {
            float m = s1.x * invN; float v = s2.x * invN - m * m;
            r.x = fmaf(((float)xh.x - m) * rsqrtf(v + LN_EPS), g.x, b.x);
        }
        {
            float m = s1.y * invN; float v = s2.y * invN - m * m;
            r.y = fmaf(((float)xh.y - m) * rsqrtf(v + LN_EPS), g.y, b.y);
        }
        {
            float m = s1.z * invN; float v = s2.z * invN - m * m;
            r.z = fmaf(((float)xh.z - m) * rsqrtf(v + LN_EPS), g.z, b.z);
        }
        {
            float m = s1.w * invN; float v = s2.w * invN - m * m;
            r.w = fmaf(((float)xh.w - m) * rsqrtf(v + LN_EPS), g.w, b.w);
        }
        if (relu) {
            r.x = fmaxf(r.x, 0.f); r.y = fmaxf(r.y, 0.f);
            r.z = fmaxf(r.z, 0.f); r.w = fmaxf(r.w, 0.f);
        }
        if (out16) {
            half4v o;
            o.x = (_Float16)r.x; o.y = (_Float16)r.y;
            o.z = (_Float16)r.z; o.w = (_Float16)r.w;
            *(half4v*)&out16[(size_t)idx * 4] = o;
        } else {
            ((float4*)out32)[idx] = r;
        }
    }
}

extern "C" void kernel_launch(void* const* d_in, const int* in_sizes, int n_in,
                              void* d_out, int out_size, void* d_ws, size_t ws_size,
                              hipStream_t stream)
{
    const float* x       = (const float*)d_in[0];
    const int*   ei      = (const int*)d_in[1];
    const float* eattr   = (const float*)d_in[2];
    const float* node_W  = (const float*)d_in[3];
    const float* node_b  = (const float*)d_in[4];
    const float* node_g  = (const float*)d_in[5];
    const float* node_be = (const float*)d_in[6];
    const float* edge_W  = (const float*)d_in[7];
    const float* edge_b  = (const float*)d_in[8];
    const float* edge_g  = (const float*)d_in[9];
    const float* edge_be = (const float*)d_in[10];
    const float* sl_attr = (const float*)d_in[11];
    const float* W1      = (const float*)d_in[12];
    const float* b1      = (const float*)d_in[13];
    const float* W2      = (const float*)d_in[14];
    const float* b2      = (const float*)d_in[15];
    const float* bn_g    = (const float*)d_in[16];
    const float* bn_b    = (const float*)d_in[17];

    const int N = in_sizes[0] / NODED;
    const int E = in_sizes[1] / 2;

    // explicit 16B-aligned workspace layout
    char* base = (char*)d_ws;
    size_t off = 0;
    auto take = [&](size_t nbytes) -> void* {
        void* p = base + off;
        off = (off + nbytes + 15) & ~(size_t)15;
        return p;
    };
    _Float16* h16  = (_Float16*)take((size_t)N * HD * 2); // node features (fp16)
    _Float16* hl16 = (_Float16*)take((size_t)N * HD * 2); // mlp2 out (pre-BN, fp16)
    __bf16* aghi   = (__bf16*)take((size_t)N * HD * 2);    // aggr bf16 hi
    __bf16* aglo   = (__bf16*)take((size_t)N * HD * 2);
    _Float16* z16  = (_Float16*)take((size_t)N * 256 * 2); // mlp1 out fp16
    __bf16* xhi    = (__bf16*)take((size_t)N * NODED * 2);
    __bf16* xlo    = (__bf16*)take((size_t)N * NODED * 2);
    float*  slv3   = (float*)take(3 * HD * 4);
    float*  stats  = (float*)take(3 * 256 * 4);
    int*    cnt    = (int*)take((size_t)N * 4);
    int*    cursor = (int*)take((size_t)N * 4);
    int*    bsum   = (int*)take(256 * 4);
    int*    boff   = (int*)take(256 * 4);
    int*    rs     = (int*)take(((size_t)N + 2) * 4);
    int2*   es     = (int2*)take((size_t)E * 8);
    unsigned* sei  = (unsigned*)take((size_t)3 * E * 4);   // packed (src16, iv-fp16)
    _Float16* attr16 = (_Float16*)take((size_t)E * EDGED * 2); // slot-permuted fp16 attrs
    _Float16* Wg16_3 = (_Float16*)take(3 * 2048 * 2);      // fp16 edge weights [c][k]
    float*  bg3    = (float*)take(3 * HD * 4);
    float*  M3     = (float*)take(3 * 256 * 4);
    float*  v3     = (float*)take(3 * 16 * 4);
    float*  s03    = (float*)take(4 * 4);
    __bf16* nWhi   = (__bf16*)take((size_t)HD * NODED * 2);
    __bf16* nWlo   = (__bf16*)take((size_t)HD * NODED * 2);
    __bf16* W1hi   = (__bf16*)take((size_t)3 * 256 * HD * 2);
    __bf16* W1lo   = (__bf16*)take((size_t)3 * 256 * HD * 2);
    _Float16* W2h16 = (_Float16*)take((size_t)3 * HD * 256 * 2);
    _Float16* W2l16 = (_Float16*)take((size_t)3 * HD * 256 * 2);

    // weight splits: node/W1 bf16 hi/lo, W2 fp16 hi/lo, x bf16 hi/lo
    wconv_k<<<(HD * NODED + 255) / 256, 256, 0, stream>>>(node_W, nWhi, nWlo, HD * NODED);
    wconv_k<<<(3 * 256 * HD + 255) / 256, 256, 0, stream>>>(W1, W1hi, W1lo, 3 * 256 * HD);
    wconv16_k<<<(3 * 256 * HD + 255) / 256, 256, 0, stream>>>(W2, W2h16, W2l16, 3 * 256 * HD);
    wconv_k<<<((int)((size_t)N * NODED + 255) / 256), 256, 0, stream>>>(x, xhi, xlo, N * NODED);

    // edge-LN precompute + self-loop embed + fp16 weights (all 3 layers)
    prep_k<<<3, 256, 0, stream>>>(edge_W, edge_b, edge_g, edge_be, sl_attr,
                                  Wg16_3, bg3, M3, v3, s03, slv3);

    // ---- CSR build ----
    const int eblocks = (E + 255) / 256;
    const int nblocks = (N + 255) / 256;
    hipMemsetAsync(cnt, 0, (size_t)N * sizeof(int), stream);
    hist_k<<<eblocks, 256, 0, stream>>>(ei, cnt, E);
    scan1_k<<<nblocks, 256, 0, stream>>>(cnt, rs, bsum, N);
    scan2_k<<<1, 256, 0, stream>>>(bsum, boff, nblocks);
    scan3_k<<<nblocks, 256, 0, stream>>>(rs, cursor, boff, N, E);
    scatter_k<<<eblocks, 256, 0, stream>>>(ei, cursor, es, E);

    // per-slot packed (src, iv) for all 3 layers + permuted fp16 attr stream
    einv_k<<<eblocks, 256, 0, stream>>>(es, eattr, M3, v3, s03, sei, attr16, E);

    const int total4  = N * (HD / 4);
    const int vblocks = (total4 + 255) / 256;
    const int gb128   = (N + 127) / 128;
    int pgrid = (N + 3) / 4;
    if (pgrid > 2048) pgrid = 2048;           // persistent: 8192 waves

    // node embed: fused Linear (MFMA) + LN + ReLU -> fp16 h
    nemb_k<<<gb128, 256, 0, stream>>>(xhi, xlo, nWhi, nWlo, node_b,
                                      node_g, node_be, h16, N);

    hipMemsetAsync(stats, 0, 3 * 256 * sizeof(float), stream);

    for (int l = 0; l < 3; ++l) {
        pull9_k<<<pgrid, 256, 0, stream>>>(h16, rs, attr16, sei + (size_t)l * E,
                                           slv3 + l * HD, Wg16_3 + (size_t)l * 2048,
                                           bg3 + l * HD, edge_be + l * HD,
                                           aghi, aglo, N);

        // mlp1: bf16 hi/lo A x bf16 hi/lo W -> gelu -> fp16 z
        mgemm_k<HD, 256, 1, 0, 0, 2><<<dim3(gb128, 4), 256, 0, stream>>>(
            aghi, aglo, W1hi + (size_t)l * 256 * HD, W1lo + (size_t)l * 256 * HD,
            b1 + l * 256, nullptr, z16, N, nullptr);

        // mlp2: fp16 A x fp16 hi/lo W -> fp16 hl + fp32 stats
        mgemm_k<256, HD, 0, 1, 1, 2><<<dim3(gb128, 2), 256, 0, stream>>>(
            z16, nullptr, W2h16 + (size_t)l * HD * 256, W2l16 + (size_t)l * HD * 256,
            b2 + l * HD, nullptr, hl16, N, stats + l * 256);

        bn_k<<<vblocks, 256, 0, stream>>>(hl16, stats + l * 256,
                                          bn_g + l * HD, bn_b + l * HD,
                                          (float*)d_out, (l < 2) ? h16 : nullptr,
                                          total4, 1.f / N, (l < 2) ? 1 : 0);
    }
}